// Round 5
// baseline (3764.090 us; speedup 1.0000x reference)
//
#include <hip/hip_runtime.h>
#include <hip/hip_bf16.h>

// ---------------------------------------------------------------------------
// VectorFieldAttention on MI355X — round 5 (fp32 inputs CONFIRMED; fp32 output)
//
// R4 proved inputs are fp32 (NaN vanished with dtype-branched loads) and the
// residual error 7.156 == max|ref[i]-ref[2i+1]| proved the harness reads
// d_out as float32. This round: fuse writes f32 (dtype-dispatched), comb
// moves from d_out into ws (aliasing d_out at different byte offsets raced).
//
// Pipeline: detect -> cvtw -> conv1 -> conv2 -> zeroacc -> mha(atomic acc)
//           -> fuse(-> d_out f32)
// ws: [flag @0, 1KB][wf f32 @1024, 592,896B][comb bf16 @593,920, 16,777,216B]
//     [region @17,371,136: hidden bf16 8.39MB overlapped by acc f32 33.55MB]
//     total 50,925,568 B
// ---------------------------------------------------------------------------

#define HW 16384           // 128*128
#define NSEQ 3844          // 961 windows * 4 batch

// f32 weight file offsets (floats)
#define WF_IPW 0
#define WF_IPB 49152
#define WF_OPW 49536
#define WF_OPB 65920
#define WF_FCW 66048
#define WF_FCB 74240
#define WF_MW1 74304
#define WF_MB1 92736
#define WF_AW1 92768
#define WF_AB1 111200
#define WF_MW2 111232
#define WF_MB2 129664
#define WF_AW2 129728
#define WF_AB2 148160
#define WF_TOTAL 148224

__device__ __forceinline__ float bfu(unsigned short u) {
    union { unsigned int i; float f; } v; v.i = ((unsigned int)u) << 16; return v.f;
}
__device__ __forceinline__ unsigned short fbf(float f) {
    union { float f; unsigned int i; } v; v.f = f;
    unsigned int x = v.i;
    return (unsigned short)((x + 0x7fffu + ((x >> 16) & 1u)) >> 16);
}
// dtype-dispatched input load (f32 flag is wave-uniform)
__device__ __forceinline__ float ldin(const void* p, long long i, bool f32) {
    return f32 ? ((const float*)p)[i] : bfu(((const unsigned short*)p)[i]);
}
// unpack 8 bf16 (as uint4) -> 8 f32
__device__ __forceinline__ void unp8(uint4 u, float* x) {
    union { unsigned int i; float f; } a;
    a.i = u.x << 16;         x[0] = a.f;
    a.i = u.x & 0xffff0000u; x[1] = a.f;
    a.i = u.y << 16;         x[2] = a.f;
    a.i = u.y & 0xffff0000u; x[3] = a.f;
    a.i = u.z << 16;         x[4] = a.f;
    a.i = u.z & 0xffff0000u; x[5] = a.f;
    a.i = u.w << 16;         x[6] = a.f;
    a.i = u.w & 0xffff0000u; x[7] = a.f;
}

// ------------------------------------------------------------- K-1: detect
// bf16 N(0,1) data: exponent fields cluster near 0x7F -> bad ~ 0.
// fp32 N(0,1) data read as ushorts: low-halves have ~uniform exponents -> bad ~ 2500.
__global__ __launch_bounds__(256) void detect_kernel(const unsigned short* __restrict__ vfu,
                                                     int* __restrict__ flag)
{
    __shared__ int cnt;
    if (threadIdx.x == 0) cnt = 0;
    __syncthreads();
    int bad = 0;
    for (int i = threadIdx.x; i < 8192; i += 256) {
        int e = (vfu[i] >> 7) & 0xff;
        if (e < 0x60 || e > 0xA0) ++bad;
    }
    atomicAdd(&cnt, bad);
    __syncthreads();
    if (threadIdx.x == 0) *flag = (cnt > 400) ? 1 : 0;
}

// ---------------------------------------------------------------- K0: weights
__global__ __launch_bounds__(256) void cvtw_kernel(
    const void* ipw, const void* ipb,
    const void* opw, const void* opb,
    const void* fcw, const void* fcb,
    const void* mw1, const void* mb1,
    const void* aw1, const void* ab1,
    const void* mw2, const void* mb2,
    const void* aw2, const void* ab2,
    const int* __restrict__ flag, float* __restrict__ wf)
{
    int i = blockIdx.x * 256 + threadIdx.x;
    if (i >= WF_TOTAL) return;
    const bool f32 = (*flag != 0);
    const void* src; int off;
    if      (i < WF_IPB) { src = ipw; off = WF_IPW; }
    else if (i < WF_OPW) { src = ipb; off = WF_IPB; }
    else if (i < WF_OPB) { src = opw; off = WF_OPW; }
    else if (i < WF_FCW) { src = opb; off = WF_OPB; }
    else if (i < WF_FCB) { src = fcw; off = WF_FCW; }
    else if (i < WF_MW1) { src = fcb; off = WF_FCB; }
    else if (i < WF_MB1) { src = mw1; off = WF_MW1; }
    else if (i < WF_AW1) { src = mb1; off = WF_MB1; }
    else if (i < WF_AB1) { src = aw1; off = WF_AW1; }
    else if (i < WF_MW2) { src = ab1; off = WF_AB1; }
    else if (i < WF_MB2) { src = mw2; off = WF_MW2; }
    else if (i < WF_AW2) { src = mb2; off = WF_MB2; }
    else if (i < WF_AB2) { src = aw2; off = WF_AW2; }
    else                 { src = ab2; off = WF_AB2; }
    wf[i] = ldin(src, i - off, f32);
}

// ---------------------------------------------------------------- zero acc
__global__ __launch_bounds__(256) void zeroacc_kernel(float* acc)
{
    int i = blockIdx.x * 256 + threadIdx.x;   // 8192 blocks -> 2,097,152 float4
    float4 z; z.x = 0.f; z.y = 0.f; z.z = 0.f; z.w = 0.f;
    *(float4*)(acc + (size_t)i * 4) = z;
}

// ------------------------------------------------------------- conv3x3 body
// tile 32w x 8h, 256 threads = 4 waves (8 oc each) x 64 lanes (8x8 pixel quads)
template<int IC, bool RELU>
__device__ void conv3x3_body(const void* __restrict__ in, long long in_off, bool f32,
                             const float* __restrict__ w,    // [32][IC][9]
                             const float* __restrict__ bias, // [32]
                             unsigned short* __restrict__ out)
{
    __shared__ float xs[32][10][38];
    const int t = threadIdx.x;
    const int tx0 = blockIdx.x * 32, ty0 = blockIdx.y * 8;
    const int wv = __builtin_amdgcn_readfirstlane(t >> 6);
    const int lane = t & 63;
    const int pr = lane >> 3, pcq = lane & 7;

    float acc[8][4];
#pragma unroll
    for (int oo = 0; oo < 8; ++oo)
#pragma unroll
        for (int p = 0; p < 4; ++p) acc[oo][p] = 0.f;

    for (int cc = 0; cc < IC; cc += 32) {
        if (cc) __syncthreads();
        for (int i = t; i < 32 * 340; i += 256) {
            int c = i / 340, rem = i - c * 340;
            int rr = rem / 34, cx = rem - rr * 34;
            int gy = ty0 + rr - 1, gx = tx0 + cx - 1;
            float v = 0.f;
            if (gy >= 0 && gy < 128 && gx >= 0 && gx < 128)
                v = ldin(in, in_off + (long long)(cc + c) * HW + gy * 128 + gx, f32);
            xs[c][rr][cx] = v;
        }
        __syncthreads();
        for (int c = 0; c < 32; ++c) {
            float xv[3][6];
#pragma unroll
            for (int dy = 0; dy < 3; ++dy)
#pragma unroll
                for (int dx = 0; dx < 6; ++dx)
                    xv[dy][dx] = xs[c][pr + dy][pcq * 4 + dx];
            const float* wr0 = w + (wv * 8 * IC + (cc + c)) * 9;
#pragma unroll
            for (int oo = 0; oo < 8; ++oo) {
                const float* wr = wr0 + oo * IC * 9;
#pragma unroll
                for (int dy = 0; dy < 3; ++dy)
#pragma unroll
                    for (int dx = 0; dx < 3; ++dx) {
                        float wvv = wr[dy * 3 + dx];
#pragma unroll
                        for (int p = 0; p < 4; ++p)
                            acc[oo][p] = fmaf(wvv, xv[dy][p + dx], acc[oo][p]);
                    }
            }
        }
    }
    const int px = tx0 + pcq * 4, py = ty0 + pr;
#pragma unroll
    for (int oo = 0; oo < 8; ++oo) {
        int oc = wv * 8 + oo;
        float bb = bias[oc];
        float v0 = acc[oo][0] + bb, v1 = acc[oo][1] + bb;
        float v2 = acc[oo][2] + bb, v3 = acc[oo][3] + bb;
        if (RELU) {
            v0 = fmaxf(v0, 0.f); v1 = fmaxf(v1, 0.f);
            v2 = fmaxf(v2, 0.f); v3 = fmaxf(v3, 0.f);
        }
        ushort4 pk;
        pk.x = fbf(v0); pk.y = fbf(v1); pk.z = fbf(v2); pk.w = fbf(v3);
        *(ushort4*)(out + oc * HW + py * 128 + px) = pk;
    }
}

__global__ __launch_bounds__(256) void conv1_kernel(const void* __restrict__ vf,
                                                    const float* __restrict__ wf,
                                                    const int* __restrict__ flag,
                                                    unsigned short* __restrict__ hidden)
{
    int z = blockIdx.z, b = z >> 1, br = z & 1;
    const bool f32 = (*flag != 0);
    conv3x3_body<64, true>(vf, (long long)(b * 128 + br * 64) * HW, f32,
                           wf + (br ? WF_AW1 : WF_MW1), wf + (br ? WF_AB1 : WF_MB1),
                           hidden + (b * 64 + br * 32) * HW);
}

__global__ __launch_bounds__(256) void conv2_kernel(const unsigned short* __restrict__ hidden,
                                                    const float* __restrict__ wf,
                                                    unsigned short* __restrict__ comb)
{
    int z = blockIdx.z, b = z >> 2, br = (z >> 1) & 1, hf = z & 1;
    conv3x3_body<32, false>(hidden, (long long)(b * 64 + br * 32) * HW, false,
                            wf + (br ? WF_AW2 : WF_MW2) + hf * 32 * 32 * 9,
                            wf + (br ? WF_AB2 : WF_MB2) + hf * 32,
                            comb + (b * 128 + br * 64 + hf * 32) * HW);
}

// ---------------------------------------------------------------- K3: MHA
// block = one sequence n = (ih*31+iw)*4 + b; 4 waves = 4 heads; lane = token.
// Ends with atomicAdd of coef * out-projection into acc (f32, [b][e][h][w]).
__global__ __launch_bounds__(256, 1) void mha_kernel(
    const unsigned short* __restrict__ comb,
    const float* __restrict__ wf,
    float* __restrict__ acc_g)
{
    __shared__ unsigned short Xs[64 * 136];  // tokens (stride 132); later O (stride 136)
    __shared__ unsigned short Ks[64 * 136];  // K bf16, row stride 136
    __shared__ unsigned short Vs[64 * 136];  // V bf16

    const float* ipw = wf + WF_IPW;
    const float* ipb = wf + WF_IPB;
    const float* opw = wf + WF_OPW;
    const float* opb = wf + WF_OPB;

    const int n = blockIdx.x;
    const int ihw = n >> 2, b = n & 3;
    const int ih = ihw / 31, iw = ihw - ih * 31;
    const int base = (b * 128) * HW + (ih * 4) * 128 + iw * 4;
    const int t = threadIdx.x;

    // gather tokens: X[l][e] = comb[b][e][h0+r][w0+c], l = r*8+c
    for (int idx = t; idx < 8192; idx += 256) {
        int e = idx >> 6, l = idx & 63;
        int r = l >> 3, c = l & 7;
        Xs[l * 132 + e] = comb[base + e * HW + r * 128 + c];
    }
    __syncthreads();

    const int lane = t & 63;
    const int hh = __builtin_amdgcn_readfirstlane(t >> 6);
    const int hb = hh * 32;

    // ---- QKV ----
    float accQ[32], accK[32], accV[32];
#pragma unroll
    for (int d = 0; d < 32; ++d) {
        accQ[d] = ipb[hb + d];
        accK[d] = ipb[128 + hb + d];
        accV[d] = ipb[256 + hb + d];
    }
    const unsigned short* xrow = Xs + lane * 132;
    for (int c8 = 0; c8 < 8; ++c8) {
        float x[16];
#pragma unroll
        for (int j2 = 0; j2 < 8; ++j2) {
            unsigned int u = *(const unsigned int*)(xrow + c8 * 16 + j2 * 2);
            union { unsigned int i; float f; } lo, hi;
            lo.i = u << 16; hi.i = u & 0xffff0000u;
            x[2 * j2] = lo.f; x[2 * j2 + 1] = hi.f;
        }
#pragma unroll
        for (int d = 0; d < 32; ++d) {
            const float* wq = ipw + (hb + d) * 128 + c8 * 16;
            const float* wk = wq + 128 * 128;
            const float* wv2 = wk + 128 * 128;
#pragma unroll
            for (int j = 0; j < 16; ++j) {
                accQ[d] = fmaf(x[j], wq[j], accQ[d]);
                accK[d] = fmaf(x[j], wk[j], accK[d]);
                accV[d] = fmaf(x[j], wv2[j], accV[d]);
            }
        }
    }
    float q[32];
#pragma unroll
    for (int d = 0; d < 32; ++d) q[d] = accQ[d] * 0.17677669529663687f; // 1/sqrt(32)
#pragma unroll
    for (int d = 0; d < 32; d += 2) {
        unsigned int pk = (unsigned int)fbf(accK[d]) | ((unsigned int)fbf(accK[d + 1]) << 16);
        unsigned int pv = (unsigned int)fbf(accV[d]) | ((unsigned int)fbf(accV[d + 1]) << 16);
        *(unsigned int*)(Ks + lane * 136 + hb + d) = pk;
        *(unsigned int*)(Vs + lane * 136 + hb + d) = pv;
    }
    __syncthreads();

    // ---- scores + softmax (lane = query row) ----
    float ps[64];
    float m = -1e30f;
#pragma unroll
    for (int j = 0; j < 64; ++j) {
        const unsigned short* kr = Ks + j * 136 + hb;
        float d0 = 0.f, d1 = 0.f;
#pragma unroll
        for (int u4 = 0; u4 < 4; ++u4) {
            uint4 kk = *(const uint4*)(kr + u4 * 8);
            float kv[8];
            unp8(kk, kv);
#pragma unroll
            for (int z = 0; z < 4; ++z) {
                d0 = fmaf(q[u4 * 8 + 2 * z], kv[2 * z], d0);
                d1 = fmaf(q[u4 * 8 + 2 * z + 1], kv[2 * z + 1], d1);
            }
        }
        float s = d0 + d1;
        ps[j] = s;
        m = fmaxf(m, s);
    }
    float sum = 0.f;
#pragma unroll
    for (int j = 0; j < 64; ++j) {
        float p = __expf(ps[j] - m);
        sum += p;
        ps[j] = p;
    }
    float inv = 1.f / sum;

    // ---- O = P @ V ----
    float o[32];
#pragma unroll
    for (int d = 0; d < 32; ++d) o[d] = 0.f;
#pragma unroll
    for (int j = 0; j < 64; ++j) {
        float pj = ps[j];
        const unsigned short* vr = Vs + j * 136 + hb;
#pragma unroll
        for (int u4 = 0; u4 < 4; ++u4) {
            uint4 vv4 = *(const uint4*)(vr + u4 * 8);
            float vv[8];
            unp8(vv4, vv);
#pragma unroll
            for (int z = 0; z < 8; ++z)
                o[u4 * 8 + z] = fmaf(pj, vv[z], o[u4 * 8 + z]);
        }
    }
#pragma unroll
    for (int d = 0; d < 32; d += 2) {
        unsigned int po = (unsigned int)fbf(o[d] * inv) | ((unsigned int)fbf(o[d + 1] * inv) << 16);
        *(unsigned int*)(Xs + lane * 136 + hb + d) = po;
    }
    __syncthreads();

    // ---- out projection: wave hh -> e in [hb,hb+32), row = lane ----
    float pacc[32];
#pragma unroll
    for (int i = 0; i < 32; ++i) pacc[i] = opb[hb + i];
    const unsigned short* orow = Xs + lane * 136;
    for (int c8 = 0; c8 < 8; ++c8) {
        float x[16];
        uint4 a0 = *(const uint4*)(orow + c8 * 16);
        uint4 a1 = *(const uint4*)(orow + c8 * 16 + 8);
        unp8(a0, x);
        unp8(a1, x + 8);
#pragma unroll
        for (int i = 0; i < 32; ++i) {
            const float* wr = opw + (hb + i) * 128 + c8 * 16;
#pragma unroll
            for (int j = 0; j < 16; ++j)
                pacc[i] = fmaf(x[j], wr[j], pacc[i]);
        }
    }

    // ---- closed-form scan coefficient for this lane's pixel ----
    const int r = lane >> 3, c = lane & 7;
    const int h = ih * 4 + r, w = iw * 4 + c;
    const int mh2 = h >> 2, mw2 = w >> 2;
    const int ah = (r < 4) ? 1 : 0;
    const int aw = (c < 4) ? 1 : 0;
    const int s_our = ah * 2 + aw;
    int kk = 0, jj = 0;
#pragma unroll
    for (int s = 0; s < 4; ++s) {
        bool vh = (s >> 1) ? (mh2 <= 30) : (mh2 >= 1);
        bool vw = (s & 1) ? (mw2 <= 30) : (mw2 >= 1);
        int vv = (vh && vw) ? 1 : 0;
        kk += vv;
        if (s <= s_our) jj += vv;
    }
    const int d2 = kk - jj;  // # later-applied windows covering this pixel
    const float pw = (d2 == 0) ? 1.f : (d2 == 1) ? 0.7f : (d2 == 2) ? 0.49f : 0.343f;
    const float coef = 0.3f * pw;

    float* ap = acc_g + (b * 128 + hb) * HW + h * 128 + w;
#pragma unroll
    for (int i = 0; i < 32; ++i)
        atomicAdd(ap + i * HW, coef * pacc[i]);
}

// ---------------------------------------------------------------- K4: fuse
__global__ __launch_bounds__(256) void fuse_kernel(
    const unsigned short* __restrict__ comb,
    const float* __restrict__ acc_g,
    const void* __restrict__ vf,
    const float* __restrict__ wf,
    const int* __restrict__ flag,
    void* __restrict__ outp)
{
    __shared__ float enhs[128][65];
    __shared__ float fws[64][65];
    const float* fcw = wf + WF_FCW;
    const float* fcb = wf + WF_FCB;
    const bool f32 = (*flag != 0);
    const int t = threadIdx.x;
    const int wl = t & 63;
    const int eg = __builtin_amdgcn_readfirstlane(t >> 6);
    const int h = blockIdx.y, b = blockIdx.z;
    const int w = blockIdx.x * 64 + wl;

    const int mh = h >> 2, mw = w >> 2;
    const int kh = (mh >= 1 ? 1 : 0) + (mh <= 30 ? 1 : 0);
    const int kw = (mw >= 1 ? 1 : 0) + (mw <= 30 ? 1 : 0);
    const int k = kh * kw; // 1,2,4
    const float base7 = (k == 1) ? 0.7f : (k == 2) ? 0.49f : 0.2401f;

    const int cbase = (b * 128) * HW + h * 128 + w;
#pragma unroll
    for (int i = 0; i < 32; ++i) {
        const int e = eg * 32 + i;
        enhs[e][wl] = base7 * bfu(comb[cbase + e * HW]) + acc_g[cbase + e * HW];
    }
    __syncthreads();

    // flow weights: 1x1 conv over e + sigmoid
    float a2[16];
    const int co0 = eg * 16;
#pragma unroll
    for (int i = 0; i < 16; ++i) a2[i] = fcb[co0 + i];
    for (int e = 0; e < 128; ++e) {
        float x = enhs[e][wl];
#pragma unroll
        for (int i = 0; i < 16; ++i)
            a2[i] = fmaf(x, fcw[(co0 + i) * 128 + e], a2[i]);
    }
#pragma unroll
    for (int i = 0; i < 16; ++i)
        fws[co0 + i][wl] = 1.f / (1.f + __expf(-a2[i]));
    __syncthreads();

#pragma unroll
    for (int i = 0; i < 32; ++i) {
        const int e = eg * 32 + i;
        const int idx = cbase + e * HW;
        float val = enhs[e][wl] * fws[e & 63][wl] + ldin(vf, idx, f32);
        if (f32) ((float*)outp)[idx] = val;
        else     ((unsigned short*)outp)[idx] = fbf(val);
    }
}

// ---------------------------------------------------------------------------
extern "C" void kernel_launch(void* const* d_in, const int* in_sizes, int n_in,
                              void* d_out, int out_size, void* d_ws, size_t ws_size,
                              hipStream_t stream)
{
    const void* vf  = d_in[0];
    const void* mw1 = d_in[1];
    const void* mb1 = d_in[2];
    const void* mw2 = d_in[3];
    const void* mb2 = d_in[4];
    const void* aw1 = d_in[5];
    const void* ab1 = d_in[6];
    const void* aw2 = d_in[7];
    const void* ab2 = d_in[8];
    const void* ipw = d_in[9];
    const void* ipb = d_in[10];
    const void* opw = d_in[11];
    const void* opb = d_in[12];
    const void* fcw = d_in[13];
    const void* fcb = d_in[14];

    // ws layout (50,925,568 B total)
    int* flag = (int*)d_ws;                                         // @0
    float* wf = (float*)((char*)d_ws + 1024);                       // 592,896 B
    unsigned short* comb = (unsigned short*)((char*)d_ws + 593920); // 16,777,216 B
    unsigned short* hidden = (unsigned short*)((char*)d_ws + 17371136);
    float* acc = (float*)((char*)d_ws + 17371136);                  // overlaps hidden

    detect_kernel<<<1, 256, 0, stream>>>((const unsigned short*)vf, flag);
    cvtw_kernel<<<(WF_TOTAL + 255) / 256, 256, 0, stream>>>(
        ipw, ipb, opw, opb, fcw, fcb, mw1, mb1, aw1, ab1, mw2, mb2, aw2, ab2, flag, wf);
    conv1_kernel<<<dim3(4, 16, 8), 256, 0, stream>>>(vf, wf, flag, hidden);
    conv2_kernel<<<dim3(4, 16, 16), 256, 0, stream>>>(hidden, wf, comb);
    zeroacc_kernel<<<8192, 256, 0, stream>>>(acc);
    mha_kernel<<<NSEQ, 256, 0, stream>>>(comb, wf, acc);
    fuse_kernel<<<dim3(2, 128, 4), 256, 0, stream>>>(comb, acc, vf, wf, flag, d_out);
}

// Round 6
// 1276.035 us; speedup vs baseline: 2.9498x; 2.9498x over previous
//
#include <hip/hip_runtime.h>
#include <hip/hip_bf16.h>

// ---------------------------------------------------------------------------
// VectorFieldAttention on MI355X — round 6 (MFMA MHA)
//
// r5 passed (absmax 0.031) at 3764 us with mha_kernel = 3512 us, MfmaUtil=0,
// VALUBusy=33%, occupancy 11.5% -> latency-bound scalar-VALU. This round puts
// all five MHA GEMMs (QKV, S=QK^T, PV, out-proj) on v_mfma_f32_16x16x32_bf16.
//
// mha structure (block = one window*batch, 4 waves = 4 heads):
//   X chunk-staged (4 x 32 e-dims) -> QKV = W.X^T on MFMA (acc in VGPRs)
//   -> Q,K ([tok][d] s40), V^T ([d][tok] s72) in LDS -> S^T = K.Q^T (scaled)
//   -> softmax (shfl_xor 16/32) -> P ([q_tok][k_tok] s72, overlays Q+K)
//   -> O = P.V -> O LDS [tok][e] s136 -> out-proj O.Wo^T (bias folded into
//   fuse via sum_j coef_j = 1-0.7^k) -> coef-weighted atomicAdd into acc.
// LDS = 64,512 B (2 blocks/CU). bf16 weight copies live in wf's (now unused)
// f32 ipw/opw slots — ws layout unchanged from r5.
// ---------------------------------------------------------------------------

#define HW 16384           // 128*128
#define NSEQ 3844          // 961 windows * 4 batch

// f32 weight file offsets (floats)
#define WF_IPW 0
#define WF_IPB 49152
#define WF_OPW 49536
#define WF_OPB 65920
#define WF_FCW 66048
#define WF_FCB 74240
#define WF_MW1 74304
#define WF_MB1 92736
#define WF_AW1 92768
#define WF_AB1 111200
#define WF_MW2 111232
#define WF_MB2 129664
#define WF_AW2 129728
#define WF_AB2 148160
#define WF_TOTAL 148224

typedef __bf16 bf16x8 __attribute__((ext_vector_type(8)));
typedef float f32x4 __attribute__((ext_vector_type(4)));
typedef unsigned int uint2v __attribute__((ext_vector_type(2)));
typedef unsigned int uint4v __attribute__((ext_vector_type(4)));

#define MFMA16(a, b, c) __builtin_amdgcn_mfma_f32_16x16x32_bf16((a), (b), (c), 0, 0, 0)

__device__ __forceinline__ float bfu(unsigned short u) {
    union { unsigned int i; float f; } v; v.i = ((unsigned int)u) << 16; return v.f;
}
__device__ __forceinline__ unsigned short fbf(float f) {
    union { float f; unsigned int i; } v; v.f = f;
    unsigned int x = v.i;
    return (unsigned short)((x + 0x7fffu + ((x >> 16) & 1u)) >> 16);
}
__device__ __forceinline__ float ldin(const void* p, long long i, bool f32) {
    return f32 ? ((const float*)p)[i] : bfu(((const unsigned short*)p)[i]);
}
__device__ __forceinline__ bf16x8 frag_ld(const unsigned short* p) {
    union { uint4v u; bf16x8 b; } v;
    v.u = *(const uint4v*)p;
    return v.b;
}
__device__ __forceinline__ uint2v pack4(float a, float b, float c, float d) {
    uint2v r;
    r.x = (unsigned int)fbf(a) | ((unsigned int)fbf(b) << 16);
    r.y = (unsigned int)fbf(c) | ((unsigned int)fbf(d) << 16);
    return r;
}

// ------------------------------------------------------------- K-1: detect
__global__ __launch_bounds__(256) void detect_kernel(const unsigned short* __restrict__ vfu,
                                                     int* __restrict__ flag)
{
    __shared__ int cnt;
    if (threadIdx.x == 0) cnt = 0;
    __syncthreads();
    int bad = 0;
    for (int i = threadIdx.x; i < 8192; i += 256) {
        int e = (vfu[i] >> 7) & 0xff;
        if (e < 0x60 || e > 0xA0) ++bad;
    }
    atomicAdd(&cnt, bad);
    __syncthreads();
    if (threadIdx.x == 0) *flag = (cnt > 400) ? 1 : 0;
}

// ---------------------------------------------------------------- K0: weights
// f32 table + bf16 copies of in_proj_w / out_proj_w stored INTO the (unused)
// f32 slots of ipw/opw (wqkv_bf = (ushort*)(wf+WF_IPW), wo_bf = (ushort*)(wf+WF_OPW)).
__global__ __launch_bounds__(256) void cvtw_kernel(
    const void* ipw, const void* ipb,
    const void* opw, const void* opb,
    const void* fcw, const void* fcb,
    const void* mw1, const void* mb1,
    const void* aw1, const void* ab1,
    const void* mw2, const void* mb2,
    const void* aw2, const void* ab2,
    const int* __restrict__ flag, float* __restrict__ wf)
{
    int i = blockIdx.x * 256 + threadIdx.x;
    if (i >= WF_TOTAL) return;
    const bool f32 = (*flag != 0);
    const void* src; int off;
    if      (i < WF_IPB) { src = ipw; off = WF_IPW; }
    else if (i < WF_OPW) { src = ipb; off = WF_IPB; }
    else if (i < WF_OPB) { src = opw; off = WF_OPW; }
    else if (i < WF_FCW) { src = opb; off = WF_OPB; }
    else if (i < WF_FCB) { src = fcw; off = WF_FCW; }
    else if (i < WF_MW1) { src = fcb; off = WF_FCB; }
    else if (i < WF_MB1) { src = mw1; off = WF_MW1; }
    else if (i < WF_AW1) { src = mb1; off = WF_MB1; }
    else if (i < WF_AB1) { src = aw1; off = WF_AW1; }
    else if (i < WF_MW2) { src = ab1; off = WF_AB1; }
    else if (i < WF_MB2) { src = mw2; off = WF_MW2; }
    else if (i < WF_AW2) { src = mb2; off = WF_MB2; }
    else if (i < WF_AB2) { src = aw2; off = WF_AW2; }
    else                 { src = ab2; off = WF_AB2; }
    float v = ldin(src, i - off, f32);
    if (i < WF_IPB) {
        ((unsigned short*)(wf + WF_IPW))[i] = fbf(v);           // wqkv_bf [384][128]
    } else if (i >= WF_OPW && i < WF_OPB) {
        ((unsigned short*)(wf + WF_OPW))[i - WF_OPW] = fbf(v);  // wo_bf [128][128]
    } else {
        wf[i] = v;
    }
}

// ---------------------------------------------------------------- zero acc
__global__ __launch_bounds__(256) void zeroacc_kernel(float* acc)
{
    int i = blockIdx.x * 256 + threadIdx.x;
    float4 z; z.x = 0.f; z.y = 0.f; z.z = 0.f; z.w = 0.f;
    *(float4*)(acc + (size_t)i * 4) = z;
}

// ------------------------------------------------------------- conv3x3 body
template<int IC, bool RELU>
__device__ void conv3x3_body(const void* __restrict__ in, long long in_off, bool f32,
                             const float* __restrict__ w,    // [32][IC][9]
                             const float* __restrict__ bias, // [32]
                             unsigned short* __restrict__ out)
{
    __shared__ float xs[32][10][38];
    const int t = threadIdx.x;
    const int tx0 = blockIdx.x * 32, ty0 = blockIdx.y * 8;
    const int wv = __builtin_amdgcn_readfirstlane(t >> 6);
    const int lane = t & 63;
    const int pr = lane >> 3, pcq = lane & 7;

    float acc[8][4];
#pragma unroll
    for (int oo = 0; oo < 8; ++oo)
#pragma unroll
        for (int p = 0; p < 4; ++p) acc[oo][p] = 0.f;

    for (int cc = 0; cc < IC; cc += 32) {
        if (cc) __syncthreads();
        for (int i = t; i < 32 * 340; i += 256) {
            int c = i / 340, rem = i - c * 340;
            int rr = rem / 34, cx = rem - rr * 34;
            int gy = ty0 + rr - 1, gx = tx0 + cx - 1;
            float v = 0.f;
            if (gy >= 0 && gy < 128 && gx >= 0 && gx < 128)
                v = ldin(in, in_off + (long long)(cc + c) * HW + gy * 128 + gx, f32);
            xs[c][rr][cx] = v;
        }
        __syncthreads();
        for (int c = 0; c < 32; ++c) {
            float xv[3][6];
#pragma unroll
            for (int dy = 0; dy < 3; ++dy)
#pragma unroll
                for (int dx = 0; dx < 6; ++dx)
                    xv[dy][dx] = xs[c][pr + dy][pcq * 4 + dx];
            const float* wr0 = w + (wv * 8 * IC + (cc + c)) * 9;
#pragma unroll
            for (int oo = 0; oo < 8; ++oo) {
                const float* wr = wr0 + oo * IC * 9;
#pragma unroll
                for (int dy = 0; dy < 3; ++dy)
#pragma unroll
                    for (int dx = 0; dx < 3; ++dx) {
                        float wvv = wr[dy * 3 + dx];
#pragma unroll
                        for (int p = 0; p < 4; ++p)
                            acc[oo][p] = fmaf(wvv, xv[dy][p + dx], acc[oo][p]);
                    }
            }
        }
    }
    const int px = tx0 + pcq * 4, py = ty0 + pr;
#pragma unroll
    for (int oo = 0; oo < 8; ++oo) {
        int oc = wv * 8 + oo;
        float bb = bias[oc];
        float v0 = acc[oo][0] + bb, v1 = acc[oo][1] + bb;
        float v2 = acc[oo][2] + bb, v3 = acc[oo][3] + bb;
        if (RELU) {
            v0 = fmaxf(v0, 0.f); v1 = fmaxf(v1, 0.f);
            v2 = fmaxf(v2, 0.f); v3 = fmaxf(v3, 0.f);
        }
        ushort4 pk;
        pk.x = fbf(v0); pk.y = fbf(v1); pk.z = fbf(v2); pk.w = fbf(v3);
        *(ushort4*)(out + oc * HW + py * 128 + px) = pk;
    }
}

__global__ __launch_bounds__(256) void conv1_kernel(const void* __restrict__ vf,
                                                    const float* __restrict__ wf,
                                                    const int* __restrict__ flag,
                                                    unsigned short* __restrict__ hidden)
{
    int z = blockIdx.z, b = z >> 1, br = z & 1;
    const bool f32 = (*flag != 0);
    conv3x3_body<64, true>(vf, (long long)(b * 128 + br * 64) * HW, f32,
                           wf + (br ? WF_AW1 : WF_MW1), wf + (br ? WF_AB1 : WF_MB1),
                           hidden + (b * 64 + br * 32) * HW);
}

__global__ __launch_bounds__(256) void conv2_kernel(const unsigned short* __restrict__ hidden,
                                                    const float* __restrict__ wf,
                                                    unsigned short* __restrict__ comb)
{
    int z = blockIdx.z, b = z >> 2, br = (z >> 1) & 1, hf = z & 1;
    conv3x3_body<32, false>(hidden, (long long)(b * 64 + br * 32) * HW, false,
                            wf + (br ? WF_AW2 : WF_MW2) + hf * 32 * 32 * 9,
                            wf + (br ? WF_AB2 : WF_MB2) + hf * 32,
                            comb + (b * 128 + br * 64 + hf * 32) * HW);
}

// ---------------------------------------------------------------- K3: MHA (MFMA)
// LDS layout (ushort idx), total 32,256 ushorts = 64,512 B:
//   Xs   @0                 [64][40]  e-chunk staging (stride 40 = 16B-aligned rows)
//   head h @ HB = 2560+h*7424:
//     Q  @HB        [64][40]   (overlaid by P [64 q_tok][72] after scores)
//     K  @HB+2560   [64][40]
//     V^T@HB+5120   [32][72]   ([d][tok])
//   O    @2560 [64][136]  (overlays heads 0-1 after barrier; all QKVP dead)
__global__ __launch_bounds__(256, 1) void mha_kernel(
    const unsigned short* __restrict__ comb,
    const float* __restrict__ wf,
    float* __restrict__ acc_g)
{
    __shared__ unsigned short lds[32256];

    const unsigned short* wqkv = (const unsigned short*)(wf + WF_IPW); // [384][128] bf16
    const unsigned short* wo   = (const unsigned short*)(wf + WF_OPW); // [128][128] bf16

    const int n = blockIdx.x;
    const int ihw = n >> 2, bb = n & 3;
    const int ih = ihw / 31, iw = ihw - ih * 31;
    const int base = (bb * 128) * HW + (ih * 4) * 128 + iw * 4;
    const int t = threadIdx.x;
    const int lane = t & 63, quad = lane >> 4, l16 = lane & 15;
    const int hh = __builtin_amdgcn_readfirstlane(t >> 6);
    const int hb = hh * 32;
    const int HB = 2560 + hh * 7424;

    // ---- QKV: D = Wqkv . X^T  (rows = qkv dim, cols = token) ----
    int rowb[6];
    f32x4 acc[6][4];
#pragma unroll
    for (int nt = 0; nt < 6; ++nt) {
        int rb = (nt < 2) ? (hb + nt * 16)
               : (nt < 4) ? (128 + hb + (nt - 2) * 16)
                          : (256 + hb + (nt - 4) * 16);
        rowb[nt] = rb;
        f32x4 b4;
        b4[0] = wf[WF_IPB + rb + quad * 4 + 0];
        b4[1] = wf[WF_IPB + rb + quad * 4 + 1];
        b4[2] = wf[WF_IPB + rb + quad * 4 + 2];
        b4[3] = wf[WF_IPB + rb + quad * 4 + 3];
#pragma unroll
        for (int mt = 0; mt < 4; ++mt) acc[nt][mt] = b4;
    }

    for (int kc = 0; kc < 4; ++kc) {
        __syncthreads();
        // gather e-chunk: Xs[tok][e_l] = comb[e][pix(tok)]
#pragma unroll
        for (int i = 0; i < 8; ++i) {
            int idx = t + i * 256;
            int e_l = idx >> 6, tok = idx & 63;
            lds[tok * 40 + e_l] = comb[base + (kc * 32 + e_l) * HW + (tok >> 3) * 128 + (tok & 7)];
        }
        __syncthreads();
        bf16x8 bx[4];
#pragma unroll
        for (int mt = 0; mt < 4; ++mt)
            bx[mt] = frag_ld(&lds[(mt * 16 + l16) * 40 + quad * 8]);
#pragma unroll
        for (int nt = 0; nt < 6; ++nt) {
            bf16x8 aw = frag_ld(&wqkv[(rowb[nt] + l16) * 128 + kc * 32 + quad * 8]);
#pragma unroll
            for (int mt = 0; mt < 4; ++mt)
                acc[nt][mt] = MFMA16(aw, bx[mt], acc[nt][mt]);
        }
    }

    // ---- write Q,K ([tok][d] stride 40, b64 packs) and V^T ([d][tok] s72) ----
#pragma unroll
    for (int nt = 0; nt < 2; ++nt)
#pragma unroll
        for (int mt = 0; mt < 4; ++mt) {
            int tok = mt * 16 + l16;
            *(uint2v*)&lds[HB + tok * 40 + nt * 16 + quad * 4] =
                pack4(acc[nt][mt][0], acc[nt][mt][1], acc[nt][mt][2], acc[nt][mt][3]);
            *(uint2v*)&lds[HB + 2560 + tok * 40 + nt * 16 + quad * 4] =
                pack4(acc[nt + 2][mt][0], acc[nt + 2][mt][1], acc[nt + 2][mt][2], acc[nt + 2][mt][3]);
        }
#pragma unroll
    for (int nt = 0; nt < 2; ++nt)
#pragma unroll
        for (int mt = 0; mt < 4; ++mt)
#pragma unroll
            for (int r = 0; r < 4; ++r)
                lds[HB + 5120 + (nt * 16 + quad * 4 + r) * 72 + mt * 16 + l16] =
                    fbf(acc[nt + 4][mt][r]);
    __asm__ volatile("s_waitcnt lgkmcnt(0)" ::: "memory");  // within-wave QKV handoff

    // ---- scores: S^T = K . Q^T (rows = k_tok, cols = q_tok), then scale ----
    bf16x8 ak[4], bq[4];
#pragma unroll
    for (int mtk = 0; mtk < 4; ++mtk)
        ak[mtk] = frag_ld(&lds[HB + 2560 + (mtk * 16 + l16) * 40 + quad * 8]);
#pragma unroll
    for (int ntq = 0; ntq < 4; ++ntq)
        bq[ntq] = frag_ld(&lds[HB + (ntq * 16 + l16) * 40 + quad * 8]);
    f32x4 sc[4][4];
    {
        f32x4 zz = {0.f, 0.f, 0.f, 0.f};
#pragma unroll
        for (int mtk = 0; mtk < 4; ++mtk)
#pragma unroll
            for (int ntq = 0; ntq < 4; ++ntq)
                sc[mtk][ntq] = MFMA16(ak[mtk], bq[ntq], zz);
    }

    // ---- softmax over k_tok per q_tok; write P [q_tok][k_tok] s72 over Q/K ----
    const float scale = 0.17677669529663687f;  // 32^-0.5
#pragma unroll
    for (int ntq = 0; ntq < 4; ++ntq) {
        float m0 = -1e30f;
#pragma unroll
        for (int mtk = 0; mtk < 4; ++mtk)
#pragma unroll
            for (int r = 0; r < 4; ++r) {
                sc[mtk][ntq][r] *= scale;
                m0 = fmaxf(m0, sc[mtk][ntq][r]);
            }
        m0 = fmaxf(m0, __shfl_xor(m0, 16));
        m0 = fmaxf(m0, __shfl_xor(m0, 32));
        float s0 = 0.f;
#pragma unroll
        for (int mtk = 0; mtk < 4; ++mtk)
#pragma unroll
            for (int r = 0; r < 4; ++r) {
                float p = __expf(sc[mtk][ntq][r] - m0);
                sc[mtk][ntq][r] = p;
                s0 += p;
            }
        s0 += __shfl_xor(s0, 16);
        s0 += __shfl_xor(s0, 32);
        float inv = 1.f / s0;
#pragma unroll
        for (int mtk = 0; mtk < 4; ++mtk)
            *(uint2v*)&lds[HB + (ntq * 16 + l16) * 72 + mtk * 16 + quad * 4] =
                pack4(sc[mtk][ntq][0] * inv, sc[mtk][ntq][1] * inv,
                      sc[mtk][ntq][2] * inv, sc[mtk][ntq][3] * inv);
    }
    __asm__ volatile("s_waitcnt lgkmcnt(0)" ::: "memory");  // P handoff

    // ---- O = P . V  (A = P [q_tok][k_tok] s72, B = V^T [d][tok] s72) ----
    f32x4 ov[4][2];
#pragma unroll
    for (int mt = 0; mt < 4; ++mt)
#pragma unroll
        for (int nv = 0; nv < 2; ++nv) { f32x4 zz = {0.f,0.f,0.f,0.f}; ov[mt][nv] = zz; }
#pragma unroll
    for (int ks = 0; ks < 2; ++ks) {
        bf16x8 ap[4];
#pragma unroll
        for (int mt = 0; mt < 4; ++mt)
            ap[mt] = frag_ld(&lds[HB + (mt * 16 + l16) * 72 + ks * 32 + quad * 8]);
#pragma unroll
        for (int nv = 0; nv < 2; ++nv) {
            bf16x8 bv = frag_ld(&lds[HB + 5120 + (nv * 16 + l16) * 72 + ks * 32 + quad * 8]);
#pragma unroll
            for (int mt = 0; mt < 4; ++mt)
                ov[mt][nv] = MFMA16(ap[mt], bv, ov[mt][nv]);
        }
    }
    __syncthreads();  // all waves done with QKV/P/V before O overlays heads 0-1

    // ---- O -> LDS [tok][e] stride 136 @2560 ----
#pragma unroll
    for (int mt = 0; mt < 4; ++mt)
#pragma unroll
        for (int nv = 0; nv < 2; ++nv)
#pragma unroll
            for (int r = 0; r < 4; ++r)
                lds[2560 + (mt * 16 + quad * 4 + r) * 136 + hb + nv * 16 + l16] =
                    fbf(ov[mt][nv][r]);
    __syncthreads();

    // ---- out-proj: D = O . Wo^T (no bias; folded into fuse) ----
    f32x4 dp[4][2];
#pragma unroll
    for (int mt = 0; mt < 4; ++mt)
#pragma unroll
        for (int nl = 0; nl < 2; ++nl) { f32x4 zz = {0.f,0.f,0.f,0.f}; dp[mt][nl] = zz; }
#pragma unroll
    for (int ks = 0; ks < 4; ++ks) {
        bf16x8 af[4];
#pragma unroll
        for (int mt = 0; mt < 4; ++mt)
            af[mt] = frag_ld(&lds[2560 + (mt * 16 + l16) * 136 + ks * 32 + quad * 8]);
#pragma unroll
        for (int nl = 0; nl < 2; ++nl) {
            int erow = hb + nl * 16 + l16;
            bf16x8 bw = frag_ld(&wo[erow * 128 + ks * 32 + quad * 8]);
#pragma unroll
            for (int mt = 0; mt < 4; ++mt)
                dp[mt][nl] = MFMA16(af[mt], bw, dp[mt][nl]);
        }
    }

    // ---- epilogue: coef(token) * value -> atomicAdd into acc_g ----
#pragma unroll
    for (int mt = 0; mt < 4; ++mt)
#pragma unroll
        for (int r = 0; r < 4; ++r) {
            int tok = mt * 16 + quad * 4 + r;
            int pr = tok >> 3, pc = tok & 7;
            int hpix = ih * 4 + pr, wpix = iw * 4 + pc;
            int mh2 = hpix >> 2, mw2 = wpix >> 2;
            int ah = (pr < 4) ? 1 : 0;
            int aw = (pc < 4) ? 1 : 0;
            int s_our = ah * 2 + aw;
            int kk = 0, jj = 0;
#pragma unroll
            for (int s = 0; s < 4; ++s) {
                bool vh = (s >> 1) ? (mh2 <= 30) : (mh2 >= 1);
                bool vw = (s & 1) ? (mw2 <= 30) : (mw2 >= 1);
                int vv = (vh && vw) ? 1 : 0;
                kk += vv;
                if (s <= s_our) jj += vv;
            }
            int d2 = kk - jj;
            float pw = (d2 == 0) ? 1.f : (d2 == 1) ? 0.7f : (d2 == 2) ? 0.49f : 0.343f;
            float coef = 0.3f * pw;
#pragma unroll
            for (int nl = 0; nl < 2; ++nl) {
                int e = hb + nl * 16 + l16;
                atomicAdd(acc_g + (size_t)(bb * 128 + e) * HW + hpix * 128 + wpix,
                          coef * dp[mt][nl][r]);
            }
        }
}

// ---------------------------------------------------------------- K4: fuse
__global__ __launch_bounds__(256) void fuse_kernel(
    const unsigned short* __restrict__ comb,
    const float* __restrict__ acc_g,
    const void* __restrict__ vf,
    const float* __restrict__ wf,
    const int* __restrict__ flag,
    void* __restrict__ outp)
{
    __shared__ float enhs[128][65];
    __shared__ float fws[64][65];
    const float* fcw = wf + WF_FCW;
    const float* fcb = wf + WF_FCB;
    const bool f32 = (*flag != 0);
    const int t = threadIdx.x;
    const int wl = t & 63;
    const int eg = __builtin_amdgcn_readfirstlane(t >> 6);
    const int h = blockIdx.y, b = blockIdx.z;
    const int w = blockIdx.x * 64 + wl;

    const int mh = h >> 2, mw = w >> 2;
    const int kh = (mh >= 1 ? 1 : 0) + (mh <= 30 ? 1 : 0);
    const int kw = (mw >= 1 ? 1 : 0) + (mw <= 30 ? 1 : 0);
    const int k = kh * kw; // 1,2,4
    const float base7 = (k == 1) ? 0.7f : (k == 2) ? 0.49f : 0.2401f;
    const float bias_c = 1.f - base7;  // sum_j coef_j (out-proj bias weight)

    const int cbase = (b * 128) * HW + h * 128 + w;
#pragma unroll
    for (int i = 0; i < 32; ++i) {
        const int e = eg * 32 + i;
        enhs[e][wl] = base7 * bfu(comb[cbase + e * HW]) + acc_g[cbase + e * HW]
                    + bias_c * wf[WF_OPB + e];
    }
    __syncthreads();

    float a2[16];
    const int co0 = eg * 16;
#pragma unroll
    for (int i = 0; i < 16; ++i) a2[i] = fcb[co0 + i];
    for (int e = 0; e < 128; ++e) {
        float x = enhs[e][wl];
#pragma unroll
        for (int i = 0; i < 16; ++i)
            a2[i] = fmaf(x, fcw[(co0 + i) * 128 + e], a2[i]);
    }
#pragma unroll
    for (int i = 0; i < 16; ++i)
        fws[co0 + i][wl] = 1.f / (1.f + __expf(-a2[i]));
    __syncthreads();

#pragma unroll
    for (int i = 0; i < 32; ++i) {
        const int e = eg * 32 + i;
        const int idx = cbase + e * HW;
        float val = enhs[e][wl] * fws[e & 63][wl] + ldin(vf, idx, f32);
        if (f32) ((float*)outp)[idx] = val;
        else     ((unsigned short*)outp)[idx] = fbf(val);
    }
}

// ---------------------------------------------------------------------------
extern "C" void kernel_launch(void* const* d_in, const int* in_sizes, int n_in,
                              void* d_out, int out_size, void* d_ws, size_t ws_size,
                              hipStream_t stream)
{
    const void* vf  = d_in[0];
    const void* mw1 = d_in[1];
    const void* mb1 = d_in[2];
    const void* mw2 = d_in[3];
    const void* mb2 = d_in[4];
    const void* aw1 = d_in[5];
    const void* ab1 = d_in[6];
    const void* aw2 = d_in[7];
    const void* ab2 = d_in[8];
    const void* ipw = d_in[9];
    const void* ipb = d_in[10];
    const void* opw = d_in[11];
    const void* opb = d_in[12];
    const void* fcw = d_in[13];
    const void* fcb = d_in[14];

    // ws layout (50,925,568 B total, same as r5)
    int* flag = (int*)d_ws;                                         // @0
    float* wf = (float*)((char*)d_ws + 1024);                       // 592,896 B
    unsigned short* comb = (unsigned short*)((char*)d_ws + 593920); // 16,777,216 B
    unsigned short* hidden = (unsigned short*)((char*)d_ws + 17371136);
    float* acc = (float*)((char*)d_ws + 17371136);                  // overlaps hidden

    detect_kernel<<<1, 256, 0, stream>>>((const unsigned short*)vf, flag);
    cvtw_kernel<<<(WF_TOTAL + 255) / 256, 256, 0, stream>>>(
        ipw, ipb, opw, opb, fcw, fcb, mw1, mb1, aw1, ab1, mw2, mb2, aw2, ab2, flag, wf);
    conv1_kernel<<<dim3(4, 16, 8), 256, 0, stream>>>(vf, wf, flag, hidden);
    conv2_kernel<<<dim3(4, 16, 16), 256, 0, stream>>>(hidden, wf, comb);
    zeroacc_kernel<<<8192, 256, 0, stream>>>(acc);
    mha_kernel<<<NSEQ, 256, 0, stream>>>(comb, wf, acc);
    fuse_kernel<<<dim3(2, 128, 4), 256, 0, stream>>>(comb, acc, vf, wf, flag, d_out);
}

// Round 7
// 484.386 us; speedup vs baseline: 7.7708x; 2.6343x over previous
//
#include <hip/hip_runtime.h>
#include <hip/hip_bf16.h>

// ---------------------------------------------------------------------------
// VectorFieldAttention on MI355X — round 7 (coalesced atomic epilogue)
//
// r6: mha = 945 us, WRITE_SIZE = 730 MB at ~0.77 TB/s -> duration == atomic
// write-drain. Cause: e-major acc layout scattered each atomic wave-instr
// across 64 distinct 64B lines. Fix: acc becomes PIXEL-major [b][pix][e] so
// 16 lanes write 16 consecutive floats (4 lines/instr, ~16x less write amp).
// Also: X-gather vectorized (2x 8B ushort4 loads/thread instead of 32x 2B).
// fuse reads acc via contiguous float4s. All else identical to passing r6.
// ---------------------------------------------------------------------------

#define HW 16384           // 128*128
#define NSEQ 3844          // 961 windows * 4 batch

// f32 weight file offsets (floats)
#define WF_IPW 0
#define WF_IPB 49152
#define WF_OPW 49536
#define WF_OPB 65920
#define WF_FCW 66048
#define WF_FCB 74240
#define WF_MW1 74304
#define WF_MB1 92736
#define WF_AW1 92768
#define WF_AB1 111200
#define WF_MW2 111232
#define WF_MB2 129664
#define WF_AW2 129728
#define WF_AB2 148160
#define WF_TOTAL 148224

typedef __bf16 bf16x8 __attribute__((ext_vector_type(8)));
typedef float f32x4 __attribute__((ext_vector_type(4)));
typedef unsigned int uint2v __attribute__((ext_vector_type(2)));
typedef unsigned int uint4v __attribute__((ext_vector_type(4)));

#define MFMA16(a, b, c) __builtin_amdgcn_mfma_f32_16x16x32_bf16((a), (b), (c), 0, 0, 0)

__device__ __forceinline__ float bfu(unsigned short u) {
    union { unsigned int i; float f; } v; v.i = ((unsigned int)u) << 16; return v.f;
}
__device__ __forceinline__ unsigned short fbf(float f) {
    union { float f; unsigned int i; } v; v.f = f;
    unsigned int x = v.i;
    return (unsigned short)((x + 0x7fffu + ((x >> 16) & 1u)) >> 16);
}
__device__ __forceinline__ float ldin(const void* p, long long i, bool f32) {
    return f32 ? ((const float*)p)[i] : bfu(((const unsigned short*)p)[i]);
}
__device__ __forceinline__ bf16x8 frag_ld(const unsigned short* p) {
    union { uint4v u; bf16x8 b; } v;
    v.u = *(const uint4v*)p;
    return v.b;
}
__device__ __forceinline__ uint2v pack4(float a, float b, float c, float d) {
    uint2v r;
    r.x = (unsigned int)fbf(a) | ((unsigned int)fbf(b) << 16);
    r.y = (unsigned int)fbf(c) | ((unsigned int)fbf(d) << 16);
    return r;
}

// ------------------------------------------------------------- K-1: detect
__global__ __launch_bounds__(256) void detect_kernel(const unsigned short* __restrict__ vfu,
                                                     int* __restrict__ flag)
{
    __shared__ int cnt;
    if (threadIdx.x == 0) cnt = 0;
    __syncthreads();
    int bad = 0;
    for (int i = threadIdx.x; i < 8192; i += 256) {
        int e = (vfu[i] >> 7) & 0xff;
        if (e < 0x60 || e > 0xA0) ++bad;
    }
    atomicAdd(&cnt, bad);
    __syncthreads();
    if (threadIdx.x == 0) *flag = (cnt > 400) ? 1 : 0;
}

// ---------------------------------------------------------------- K0: weights
__global__ __launch_bounds__(256) void cvtw_kernel(
    const void* ipw, const void* ipb,
    const void* opw, const void* opb,
    const void* fcw, const void* fcb,
    const void* mw1, const void* mb1,
    const void* aw1, const void* ab1,
    const void* mw2, const void* mb2,
    const void* aw2, const void* ab2,
    const int* __restrict__ flag, float* __restrict__ wf)
{
    int i = blockIdx.x * 256 + threadIdx.x;
    if (i >= WF_TOTAL) return;
    const bool f32 = (*flag != 0);
    const void* src; int off;
    if      (i < WF_IPB) { src = ipw; off = WF_IPW; }
    else if (i < WF_OPW) { src = ipb; off = WF_IPB; }
    else if (i < WF_OPB) { src = opw; off = WF_OPW; }
    else if (i < WF_FCW) { src = opb; off = WF_OPB; }
    else if (i < WF_FCB) { src = fcw; off = WF_FCW; }
    else if (i < WF_MW1) { src = fcb; off = WF_FCB; }
    else if (i < WF_MB1) { src = mw1; off = WF_MW1; }
    else if (i < WF_AW1) { src = mb1; off = WF_MB1; }
    else if (i < WF_AB1) { src = aw1; off = WF_AW1; }
    else if (i < WF_MW2) { src = ab1; off = WF_AB1; }
    else if (i < WF_MB2) { src = mw2; off = WF_MW2; }
    else if (i < WF_AW2) { src = mb2; off = WF_MB2; }
    else if (i < WF_AB2) { src = aw2; off = WF_AW2; }
    else                 { src = ab2; off = WF_AB2; }
    float v = ldin(src, i - off, f32);
    if (i < WF_IPB) {
        ((unsigned short*)(wf + WF_IPW))[i] = fbf(v);           // wqkv_bf [384][128]
    } else if (i >= WF_OPW && i < WF_OPB) {
        ((unsigned short*)(wf + WF_OPW))[i - WF_OPW] = fbf(v);  // wo_bf [128][128]
    } else {
        wf[i] = v;
    }
}

// ---------------------------------------------------------------- zero acc
__global__ __launch_bounds__(256) void zeroacc_kernel(float* acc)
{
    int i = blockIdx.x * 256 + threadIdx.x;
    float4 z; z.x = 0.f; z.y = 0.f; z.z = 0.f; z.w = 0.f;
    *(float4*)(acc + (size_t)i * 4) = z;
}

// ------------------------------------------------------------- conv3x3 body
template<int IC, bool RELU>
__device__ void conv3x3_body(const void* __restrict__ in, long long in_off, bool f32,
                             const float* __restrict__ w,    // [32][IC][9]
                             const float* __restrict__ bias, // [32]
                             unsigned short* __restrict__ out)
{
    __shared__ float xs[32][10][38];
    const int t = threadIdx.x;
    const int tx0 = blockIdx.x * 32, ty0 = blockIdx.y * 8;
    const int wv = __builtin_amdgcn_readfirstlane(t >> 6);
    const int lane = t & 63;
    const int pr = lane >> 3, pcq = lane & 7;

    float acc[8][4];
#pragma unroll
    for (int oo = 0; oo < 8; ++oo)
#pragma unroll
        for (int p = 0; p < 4; ++p) acc[oo][p] = 0.f;

    for (int cc = 0; cc < IC; cc += 32) {
        if (cc) __syncthreads();
        for (int i = t; i < 32 * 340; i += 256) {
            int c = i / 340, rem = i - c * 340;
            int rr = rem / 34, cx = rem - rr * 34;
            int gy = ty0 + rr - 1, gx = tx0 + cx - 1;
            float v = 0.f;
            if (gy >= 0 && gy < 128 && gx >= 0 && gx < 128)
                v = ldin(in, in_off + (long long)(cc + c) * HW + gy * 128 + gx, f32);
            xs[c][rr][cx] = v;
        }
        __syncthreads();
        for (int c = 0; c < 32; ++c) {
            float xv[3][6];
#pragma unroll
            for (int dy = 0; dy < 3; ++dy)
#pragma unroll
                for (int dx = 0; dx < 6; ++dx)
                    xv[dy][dx] = xs[c][pr + dy][pcq * 4 + dx];
            const float* wr0 = w + (wv * 8 * IC + (cc + c)) * 9;
#pragma unroll
            for (int oo = 0; oo < 8; ++oo) {
                const float* wr = wr0 + oo * IC * 9;
#pragma unroll
                for (int dy = 0; dy < 3; ++dy)
#pragma unroll
                    for (int dx = 0; dx < 3; ++dx) {
                        float wvv = wr[dy * 3 + dx];
#pragma unroll
                        for (int p = 0; p < 4; ++p)
                            acc[oo][p] = fmaf(wvv, xv[dy][p + dx], acc[oo][p]);
                    }
            }
        }
    }
    const int px = tx0 + pcq * 4, py = ty0 + pr;
#pragma unroll
    for (int oo = 0; oo < 8; ++oo) {
        int oc = wv * 8 + oo;
        float bb = bias[oc];
        float v0 = acc[oo][0] + bb, v1 = acc[oo][1] + bb;
        float v2 = acc[oo][2] + bb, v3 = acc[oo][3] + bb;
        if (RELU) {
            v0 = fmaxf(v0, 0.f); v1 = fmaxf(v1, 0.f);
            v2 = fmaxf(v2, 0.f); v3 = fmaxf(v3, 0.f);
        }
        ushort4 pk;
        pk.x = fbf(v0); pk.y = fbf(v1); pk.z = fbf(v2); pk.w = fbf(v3);
        *(ushort4*)(out + oc * HW + py * 128 + px) = pk;
    }
}

__global__ __launch_bounds__(256) void conv1_kernel(const void* __restrict__ vf,
                                                    const float* __restrict__ wf,
                                                    const int* __restrict__ flag,
                                                    unsigned short* __restrict__ hidden)
{
    int z = blockIdx.z, b = z >> 1, br = z & 1;
    const bool f32 = (*flag != 0);
    conv3x3_body<64, true>(vf, (long long)(b * 128 + br * 64) * HW, f32,
                           wf + (br ? WF_AW1 : WF_MW1), wf + (br ? WF_AB1 : WF_MB1),
                           hidden + (b * 64 + br * 32) * HW);
}

__global__ __launch_bounds__(256) void conv2_kernel(const unsigned short* __restrict__ hidden,
                                                    const float* __restrict__ wf,
                                                    unsigned short* __restrict__ comb)
{
    int z = blockIdx.z, b = z >> 2, br = (z >> 1) & 1, hf = z & 1;
    conv3x3_body<32, false>(hidden, (long long)(b * 64 + br * 32) * HW, false,
                            wf + (br ? WF_AW2 : WF_MW2) + hf * 32 * 32 * 9,
                            wf + (br ? WF_AB2 : WF_MB2) + hf * 32,
                            comb + (b * 128 + br * 64 + hf * 32) * HW);
}

// ---------------------------------------------------------------- K3: MHA (MFMA)
// LDS layout (ushort idx), total 32,256 ushorts = 64,512 B:
//   Xs   @0                 [64][40]  e-chunk staging
//   head h @ HB = 2560+h*7424: Q @HB [64][40] (P overlays), K @HB+2560, V^T @HB+5120 [32][72]
//   O    @2560 [64][136]  (overlays heads 0-1 after barrier)
__global__ __launch_bounds__(256, 1) void mha_kernel(
    const unsigned short* __restrict__ comb,
    const float* __restrict__ wf,
    float* __restrict__ acc_g)   // PIXEL-major: [b][pix][e]
{
    __shared__ unsigned short lds[32256];

    const unsigned short* wqkv = (const unsigned short*)(wf + WF_IPW); // [384][128] bf16
    const unsigned short* wo   = (const unsigned short*)(wf + WF_OPW); // [128][128] bf16

    const int n = blockIdx.x;
    const int ihw = n >> 2, bb = n & 3;
    const int ih = ihw / 31, iw = ihw - ih * 31;
    const int base = (bb * 128) * HW + (ih * 4) * 128 + iw * 4;
    const int t = threadIdx.x;
    const int lane = t & 63, quad = lane >> 4, l16 = lane & 15;
    const int hh = __builtin_amdgcn_readfirstlane(t >> 6);
    const int hb = hh * 32;
    const int HB = 2560 + hh * 7424;

    // ---- QKV: D = Wqkv . X^T  (rows = qkv dim, cols = token) ----
    int rowb[6];
    f32x4 acc[6][4];
#pragma unroll
    for (int nt = 0; nt < 6; ++nt) {
        int rb = (nt < 2) ? (hb + nt * 16)
               : (nt < 4) ? (128 + hb + (nt - 2) * 16)
                          : (256 + hb + (nt - 4) * 16);
        rowb[nt] = rb;
        f32x4 b4;
        b4[0] = wf[WF_IPB + rb + quad * 4 + 0];
        b4[1] = wf[WF_IPB + rb + quad * 4 + 1];
        b4[2] = wf[WF_IPB + rb + quad * 4 + 2];
        b4[3] = wf[WF_IPB + rb + quad * 4 + 3];
#pragma unroll
        for (int mt = 0; mt < 4; ++mt) acc[nt][mt] = b4;
    }

    for (int kc = 0; kc < 4; ++kc) {
        __syncthreads();
        // gather e-chunk (vectorized): thread (e_l = t>>3, r = t&7) loads row r
        // of channel kc*32+e_l (8 pixels = 16B, 8B-aligned) and transposes to LDS.
        {
            const int e_l = t >> 3, r = t & 7;
            const unsigned short* gp = comb + base + (kc * 32 + e_l) * HW + r * 128;
            ushort4 a0 = *(const ushort4*)(gp);
            ushort4 a1 = *(const ushort4*)(gp + 4);
            unsigned short* xp = lds + (r * 8) * 40 + e_l;   // tok = r*8 + c
            xp[0 * 40] = a0.x; xp[1 * 40] = a0.y; xp[2 * 40] = a0.z; xp[3 * 40] = a0.w;
            xp[4 * 40] = a1.x; xp[5 * 40] = a1.y; xp[6 * 40] = a1.z; xp[7 * 40] = a1.w;
        }
        __syncthreads();
        bf16x8 bx[4];
#pragma unroll
        for (int mt = 0; mt < 4; ++mt)
            bx[mt] = frag_ld(&lds[(mt * 16 + l16) * 40 + quad * 8]);
#pragma unroll
        for (int nt = 0; nt < 6; ++nt) {
            bf16x8 aw = frag_ld(&wqkv[(rowb[nt] + l16) * 128 + kc * 32 + quad * 8]);
#pragma unroll
            for (int mt = 0; mt < 4; ++mt)
                acc[nt][mt] = MFMA16(aw, bx[mt], acc[nt][mt]);
        }
    }

    // ---- write Q,K ([tok][d] stride 40) and V^T ([d][tok] s72) ----
#pragma unroll
    for (int nt = 0; nt < 2; ++nt)
#pragma unroll
        for (int mt = 0; mt < 4; ++mt) {
            int tok = mt * 16 + l16;
            *(uint2v*)&lds[HB + tok * 40 + nt * 16 + quad * 4] =
                pack4(acc[nt][mt][0], acc[nt][mt][1], acc[nt][mt][2], acc[nt][mt][3]);
            *(uint2v*)&lds[HB + 2560 + tok * 40 + nt * 16 + quad * 4] =
                pack4(acc[nt + 2][mt][0], acc[nt + 2][mt][1], acc[nt + 2][mt][2], acc[nt + 2][mt][3]);
        }
#pragma unroll
    for (int nt = 0; nt < 2; ++nt)
#pragma unroll
        for (int mt = 0; mt < 4; ++mt)
#pragma unroll
            for (int r = 0; r < 4; ++r)
                lds[HB + 5120 + (nt * 16 + quad * 4 + r) * 72 + mt * 16 + l16] =
                    fbf(acc[nt + 4][mt][r]);
    __asm__ volatile("s_waitcnt lgkmcnt(0)" ::: "memory");  // within-wave QKV handoff

    // ---- scores: S^T = K . Q^T ----
    bf16x8 ak[4], bq[4];
#pragma unroll
    for (int mtk = 0; mtk < 4; ++mtk)
        ak[mtk] = frag_ld(&lds[HB + 2560 + (mtk * 16 + l16) * 40 + quad * 8]);
#pragma unroll
    for (int ntq = 0; ntq < 4; ++ntq)
        bq[ntq] = frag_ld(&lds[HB + (ntq * 16 + l16) * 40 + quad * 8]);
    f32x4 sc[4][4];
    {
        f32x4 zz = {0.f, 0.f, 0.f, 0.f};
#pragma unroll
        for (int mtk = 0; mtk < 4; ++mtk)
#pragma unroll
            for (int ntq = 0; ntq < 4; ++ntq)
                sc[mtk][ntq] = MFMA16(ak[mtk], bq[ntq], zz);
    }

    // ---- softmax per q_tok; P [q_tok][k_tok] s72 overlays Q/K ----
    const float scale = 0.17677669529663687f;  // 32^-0.5
#pragma unroll
    for (int ntq = 0; ntq < 4; ++ntq) {
        float m0 = -1e30f;
#pragma unroll
        for (int mtk = 0; mtk < 4; ++mtk)
#pragma unroll
            for (int r = 0; r < 4; ++r) {
                sc[mtk][ntq][r] *= scale;
                m0 = fmaxf(m0, sc[mtk][ntq][r]);
            }
        m0 = fmaxf(m0, __shfl_xor(m0, 16));
        m0 = fmaxf(m0, __shfl_xor(m0, 32));
        float s0 = 0.f;
#pragma unroll
        for (int mtk = 0; mtk < 4; ++mtk)
#pragma unroll
            for (int r = 0; r < 4; ++r) {
                float p = __expf(sc[mtk][ntq][r] - m0);
                sc[mtk][ntq][r] = p;
                s0 += p;
            }
        s0 += __shfl_xor(s0, 16);
        s0 += __shfl_xor(s0, 32);
        float inv = 1.f / s0;
#pragma unroll
        for (int mtk = 0; mtk < 4; ++mtk)
            *(uint2v*)&lds[HB + (ntq * 16 + l16) * 72 + mtk * 16 + quad * 4] =
                pack4(sc[mtk][ntq][0] * inv, sc[mtk][ntq][1] * inv,
                      sc[mtk][ntq][2] * inv, sc[mtk][ntq][3] * inv);
    }
    __asm__ volatile("s_waitcnt lgkmcnt(0)" ::: "memory");  // P handoff

    // ---- O = P . V ----
    f32x4 ov[4][2];
#pragma unroll
    for (int mt = 0; mt < 4; ++mt)
#pragma unroll
        for (int nv = 0; nv < 2; ++nv) { f32x4 zz = {0.f,0.f,0.f,0.f}; ov[mt][nv] = zz; }
#pragma unroll
    for (int ks = 0; ks < 2; ++ks) {
        bf16x8 ap[4];
#pragma unroll
        for (int mt = 0; mt < 4; ++mt)
            ap[mt] = frag_ld(&lds[HB + (mt * 16 + l16) * 72 + ks * 32 + quad * 8]);
#pragma unroll
        for (int nv = 0; nv < 2; ++nv) {
            bf16x8 bv = frag_ld(&lds[HB + 5120 + (nv * 16 + l16) * 72 + ks * 32 + quad * 8]);
#pragma unroll
            for (int mt = 0; mt < 4; ++mt)
                ov[mt][nv] = MFMA16(ap[mt], bv, ov[mt][nv]);
        }
    }
    __syncthreads();

    // ---- O -> LDS [tok][e] stride 136 @2560 ----
#pragma unroll
    for (int mt = 0; mt < 4; ++mt)
#pragma unroll
        for (int nv = 0; nv < 2; ++nv)
#pragma unroll
            for (int r = 0; r < 4; ++r)
                lds[2560 + (mt * 16 + quad * 4 + r) * 136 + hb + nv * 16 + l16] =
                    fbf(ov[mt][nv][r]);
    __syncthreads();

    // ---- out-proj: D = O . Wo^T (bias folded into fuse) ----
    f32x4 dp[4][2];
#pragma unroll
    for (int mt = 0; mt < 4; ++mt)
#pragma unroll
        for (int nl = 0; nl < 2; ++nl) { f32x4 zz = {0.f,0.f,0.f,0.f}; dp[mt][nl] = zz; }
#pragma unroll
    for (int ks = 0; ks < 4; ++ks) {
        bf16x8 af[4];
#pragma unroll
        for (int mt = 0; mt < 4; ++mt)
            af[mt] = frag_ld(&lds[2560 + (mt * 16 + l16) * 136 + ks * 32 + quad * 8]);
#pragma unroll
        for (int nl = 0; nl < 2; ++nl) {
            int erow = hb + nl * 16 + l16;
            bf16x8 bw = frag_ld(&wo[erow * 128 + ks * 32 + quad * 8]);
#pragma unroll
            for (int mt = 0; mt < 4; ++mt)
                dp[mt][nl] = MFMA16(af[mt], bw, dp[mt][nl]);
        }
    }

    // ---- epilogue: coef(token) * value -> COALESCED atomicAdd (pixel-major) ----
#pragma unroll
    for (int mt = 0; mt < 4; ++mt)
#pragma unroll
        for (int r = 0; r < 4; ++r) {
            int tok = mt * 16 + quad * 4 + r;
            int pr = tok >> 3, pc = tok & 7;
            int hpix = ih * 4 + pr, wpix = iw * 4 + pc;
            int mh2 = hpix >> 2, mw2 = wpix >> 2;
            int ah = (pr < 4) ? 1 : 0;
            int aw = (pc < 4) ? 1 : 0;
            int s_our = ah * 2 + aw;
            int kk = 0, jj = 0;
#pragma unroll
            for (int s = 0; s < 4; ++s) {
                bool vh = (s >> 1) ? (mh2 <= 30) : (mh2 >= 1);
                bool vw = (s & 1) ? (mw2 <= 30) : (mw2 >= 1);
                int vv = (vh && vw) ? 1 : 0;
                kk += vv;
                if (s <= s_our) jj += vv;
            }
            int d2 = kk - jj;
            float pw = (d2 == 0) ? 1.f : (d2 == 1) ? 0.7f : (d2 == 2) ? 0.49f : 0.343f;
            float coef = 0.3f * pw;
            // acc[b][pix][e]: 16 lanes (l16) hit 16 consecutive floats = 64B
            float* ap = acc_g + ((size_t)bb * HW + hpix * 128 + wpix) * 128 + hb + l16;
            atomicAdd(ap,      coef * dp[mt][0][r]);
            atomicAdd(ap + 16, coef * dp[mt][1][r]);
        }
}

// ---------------------------------------------------------------- K4: fuse
__global__ __launch_bounds__(256) void fuse_kernel(
    const unsigned short* __restrict__ comb,
    const float* __restrict__ acc_g,   // pixel-major [b][pix][e]
    const void* __restrict__ vf,
    const float* __restrict__ wf,
    const int* __restrict__ flag,
    void* __restrict__ outp)
{
    __shared__ float enhs[128][65];
    __shared__ float fws[64][65];
    const float* fcw = wf + WF_FCW;
    const float* fcb = wf + WF_FCB;
    const bool f32 = (*flag != 0);
    const int t = threadIdx.x;
    const int wl = t & 63;
    const int eg = __builtin_amdgcn_readfirstlane(t >> 6);
    const int h = blockIdx.y, b = blockIdx.z;
    const int w = blockIdx.x * 64 + wl;

    const int mh = h >> 2, mw = w >> 2;
    const int kh = (mh >= 1 ? 1 : 0) + (mh <= 30 ? 1 : 0);
    const int kw = (mw >= 1 ? 1 : 0) + (mw <= 30 ? 1 : 0);
    const int k = kh * kw; // 1,2,4
    const float base7 = (k == 1) ? 0.7f : (k == 2) ? 0.49f : 0.2401f;
    const float bias_c = 1.f - base7;  // sum_j coef_j (out-proj bias weight)

    const int cbase = (b * 128) * HW + h * 128 + w;
    const float* ar = acc_g + ((size_t)b * HW + h * 128 + w) * 128 + eg * 32;
#pragma unroll
    for (int i4 = 0; i4 < 8; ++i4) {
        float4 av = *(const float4*)(ar + i4 * 4);
#pragma unroll
        for (int j = 0; j < 4; ++j) {
            const int e = eg * 32 + i4 * 4 + j;
            float a = (j == 0) ? av.x : (j == 1) ? av.y : (j == 2) ? av.z : av.w;
            enhs[e][wl] = base7 * bfu(comb[cbase + e * HW]) + a + bias_c * wf[WF_OPB + e];
        }
    }
    __syncthreads();

    float a2[16];
    const int co0 = eg * 16;
#pragma unroll
    for (int i = 0; i < 16; ++i) a2[i] = fcb[co0 + i];
    for (int e = 0; e < 128; ++e) {
        float x = enhs[e][wl];
#pragma unroll
        for (int i = 0; i < 16; ++i)
            a2[i] = fmaf(x, fcw[(co0 + i) * 128 + e], a2[i]);
    }
#pragma unroll
    for (int i = 0; i < 16; ++i)
        fws[co0 + i][wl] = 1.f / (1.f + __expf(-a2[i]));
    __syncthreads();

#pragma unroll
    for (int i = 0; i < 32; ++i) {
        const int e = eg * 32 + i;
        const int idx = cbase + e * HW;
        float val = enhs[e][wl] * fws[e & 63][wl] + ldin(vf, idx, f32);
        if (f32) ((float*)outp)[idx] = val;
        else     ((unsigned short*)outp)[idx] = fbf(val);
    }
}

// ---------------------------------------------------------------------------
extern "C" void kernel_launch(void* const* d_in, const int* in_sizes, int n_in,
                              void* d_out, int out_size, void* d_ws, size_t ws_size,
                              hipStream_t stream)
{
    const void* vf  = d_in[0];
    const void* mw1 = d_in[1];
    const void* mb1 = d_in[2];
    const void* mw2 = d_in[3];
    const void* mb2 = d_in[4];
    const void* aw1 = d_in[5];
    const void* ab1 = d_in[6];
    const void* aw2 = d_in[7];
    const void* ab2 = d_in[8];
    const void* ipw = d_in[9];
    const void* ipb = d_in[10];
    const void* opw = d_in[11];
    const void* opb = d_in[12];
    const void* fcw = d_in[13];
    const void* fcb = d_in[14];

    // ws layout (50,925,568 B total, same as r6)
    int* flag = (int*)d_ws;                                         // @0
    float* wf = (float*)((char*)d_ws + 1024);                       // 592,896 B
    unsigned short* comb = (unsigned short*)((char*)d_ws + 593920); // 16,777,216 B
    unsigned short* hidden = (unsigned short*)((char*)d_ws + 17371136);
    float* acc = (float*)((char*)d_ws + 17371136);                  // overlaps hidden

    detect_kernel<<<1, 256, 0, stream>>>((const unsigned short*)vf, flag);
    cvtw_kernel<<<(WF_TOTAL + 255) / 256, 256, 0, stream>>>(
        ipw, ipb, opw, opb, fcw, fcb, mw1, mb1, aw1, ab1, mw2, mb2, aw2, ab2, flag, wf);
    conv1_kernel<<<dim3(4, 16, 8), 256, 0, stream>>>(vf, wf, flag, hidden);
    conv2_kernel<<<dim3(4, 16, 16), 256, 0, stream>>>(hidden, wf, comb);
    zeroacc_kernel<<<8192, 256, 0, stream>>>(acc);
    mha_kernel<<<NSEQ, 256, 0, stream>>>(comb, wf, acc);
    fuse_kernel<<<dim3(2, 128, 4), 256, 0, stream>>>(comb, acc, vf, wf, flag, d_out);
}

// Round 8
// 447.883 us; speedup vs baseline: 8.4042x; 1.0815x over previous
//
#include <hip/hip_runtime.h>
#include <hip/hip_bf16.h>

// ---------------------------------------------------------------------------
// VectorFieldAttention on MI355X — round 8 (atomic-free epilogue, att gather)
//
// r7: mha 159 us == ~198G atomic-RMW/s on 31.5M f32 atomics -> L2 atomic
// ceiling. This round: mha writes raw per-window out-proj to att[n][tok][e]
// (bf16, coalesced dwordx4 via LDS transpose); fuse gathers the <=4 covering
// windows per pixel with closed-form coefs (r5 logic) + folded bias. zeroacc
// kernel deleted. Xs staging double-buffered.
// ws: flag@0 | wf@1024 | comb@593,920 | hidden@17,371,136 (dead after conv2)
//     overlaid by att@17,371,136 (62,980,096 B) -> total 80,351,232 B.
// ---------------------------------------------------------------------------

#define HW 16384           // 128*128
#define NSEQ 3844          // 961 windows * 4 batch

// f32 weight file offsets (floats)
#define WF_IPW 0
#define WF_IPB 49152
#define WF_OPW 49536
#define WF_OPB 65920
#define WF_FCW 66048
#define WF_FCB 74240
#define WF_MW1 74304
#define WF_MB1 92736
#define WF_AW1 92768
#define WF_AB1 111200
#define WF_MW2 111232
#define WF_MB2 129664
#define WF_AW2 129728
#define WF_AB2 148160
#define WF_TOTAL 148224

typedef __bf16 bf16x8 __attribute__((ext_vector_type(8)));
typedef float f32x4 __attribute__((ext_vector_type(4)));
typedef unsigned int uint2v __attribute__((ext_vector_type(2)));
typedef unsigned int uint4v __attribute__((ext_vector_type(4)));

#define MFMA16(a, b, c) __builtin_amdgcn_mfma_f32_16x16x32_bf16((a), (b), (c), 0, 0, 0)

__device__ __forceinline__ float bfu(unsigned short u) {
    union { unsigned int i; float f; } v; v.i = ((unsigned int)u) << 16; return v.f;
}
__device__ __forceinline__ unsigned short fbf(float f) {
    union { float f; unsigned int i; } v; v.f = f;
    unsigned int x = v.i;
    return (unsigned short)((x + 0x7fffu + ((x >> 16) & 1u)) >> 16);
}
__device__ __forceinline__ float ldin(const void* p, long long i, bool f32) {
    return f32 ? ((const float*)p)[i] : bfu(((const unsigned short*)p)[i]);
}
__device__ __forceinline__ bf16x8 frag_ld(const unsigned short* p) {
    union { uint4v u; bf16x8 b; } v;
    v.u = *(const uint4v*)p;
    return v.b;
}
__device__ __forceinline__ uint2v pack4(float a, float b, float c, float d) {
    uint2v r;
    r.x = (unsigned int)fbf(a) | ((unsigned int)fbf(b) << 16);
    r.y = (unsigned int)fbf(c) | ((unsigned int)fbf(d) << 16);
    return r;
}
__device__ __forceinline__ void unp8(uint4v u, float* x) {
    union { unsigned int i; float f; } a;
    a.i = u.x << 16;         x[0] = a.f;
    a.i = u.x & 0xffff0000u; x[1] = a.f;
    a.i = u.y << 16;         x[2] = a.f;
    a.i = u.y & 0xffff0000u; x[3] = a.f;
    a.i = u.z << 16;         x[4] = a.f;
    a.i = u.z & 0xffff0000u; x[5] = a.f;
    a.i = u.w << 16;         x[6] = a.f;
    a.i = u.w & 0xffff0000u; x[7] = a.f;
}

// ------------------------------------------------------------- K-1: detect
__global__ __launch_bounds__(256) void detect_kernel(const unsigned short* __restrict__ vfu,
                                                     int* __restrict__ flag)
{
    __shared__ int cnt;
    if (threadIdx.x == 0) cnt = 0;
    __syncthreads();
    int bad = 0;
    for (int i = threadIdx.x; i < 8192; i += 256) {
        int e = (vfu[i] >> 7) & 0xff;
        if (e < 0x60 || e > 0xA0) ++bad;
    }
    atomicAdd(&cnt, bad);
    __syncthreads();
    if (threadIdx.x == 0) *flag = (cnt > 400) ? 1 : 0;
}

// ---------------------------------------------------------------- K0: weights
__global__ __launch_bounds__(256) void cvtw_kernel(
    const void* ipw, const void* ipb,
    const void* opw, const void* opb,
    const void* fcw, const void* fcb,
    const void* mw1, const void* mb1,
    const void* aw1, const void* ab1,
    const void* mw2, const void* mb2,
    const void* aw2, const void* ab2,
    const int* __restrict__ flag, float* __restrict__ wf)
{
    int i = blockIdx.x * 256 + threadIdx.x;
    if (i >= WF_TOTAL) return;
    const bool f32 = (*flag != 0);
    const void* src; int off;
    if      (i < WF_IPB) { src = ipw; off = WF_IPW; }
    else if (i < WF_OPW) { src = ipb; off = WF_IPB; }
    else if (i < WF_OPB) { src = opw; off = WF_OPW; }
    else if (i < WF_FCW) { src = opb; off = WF_OPB; }
    else if (i < WF_FCB) { src = fcw; off = WF_FCW; }
    else if (i < WF_MW1) { src = fcb; off = WF_FCB; }
    else if (i < WF_MB1) { src = mw1; off = WF_MW1; }
    else if (i < WF_AW1) { src = mb1; off = WF_MB1; }
    else if (i < WF_AB1) { src = aw1; off = WF_AW1; }
    else if (i < WF_MW2) { src = ab1; off = WF_AB1; }
    else if (i < WF_MB2) { src = mw2; off = WF_MW2; }
    else if (i < WF_AW2) { src = mb2; off = WF_MB2; }
    else if (i < WF_AB2) { src = aw2; off = WF_AW2; }
    else                 { src = ab2; off = WF_AB2; }
    float v = ldin(src, i - off, f32);
    if (i < WF_IPB) {
        ((unsigned short*)(wf + WF_IPW))[i] = fbf(v);           // wqkv_bf [384][128]
    } else if (i >= WF_OPW && i < WF_OPB) {
        ((unsigned short*)(wf + WF_OPW))[i - WF_OPW] = fbf(v);  // wo_bf [128][128]
    } else {
        wf[i] = v;
    }
}

// ------------------------------------------------------------- conv3x3 body
template<int IC, bool RELU>
__device__ void conv3x3_body(const void* __restrict__ in, long long in_off, bool f32,
                             const float* __restrict__ w,    // [32][IC][9]
                             const float* __restrict__ bias, // [32]
                             unsigned short* __restrict__ out)
{
    __shared__ float xs[32][10][38];
    const int t = threadIdx.x;
    const int tx0 = blockIdx.x * 32, ty0 = blockIdx.y * 8;
    const int wv = __builtin_amdgcn_readfirstlane(t >> 6);
    const int lane = t & 63;
    const int pr = lane >> 3, pcq = lane & 7;

    float acc[8][4];
#pragma unroll
    for (int oo = 0; oo < 8; ++oo)
#pragma unroll
        for (int p = 0; p < 4; ++p) acc[oo][p] = 0.f;

    for (int cc = 0; cc < IC; cc += 32) {
        if (cc) __syncthreads();
        for (int i = t; i < 32 * 340; i += 256) {
            int c = i / 340, rem = i - c * 340;
            int rr = rem / 34, cx = rem - rr * 34;
            int gy = ty0 + rr - 1, gx = tx0 + cx - 1;
            float v = 0.f;
            if (gy >= 0 && gy < 128 && gx >= 0 && gx < 128)
                v = ldin(in, in_off + (long long)(cc + c) * HW + gy * 128 + gx, f32);
            xs[c][rr][cx] = v;
        }
        __syncthreads();
        for (int c = 0; c < 32; ++c) {
            float xv[3][6];
#pragma unroll
            for (int dy = 0; dy < 3; ++dy)
#pragma unroll
                for (int dx = 0; dx < 6; ++dx)
                    xv[dy][dx] = xs[c][pr + dy][pcq * 4 + dx];
            const float* wr0 = w + (wv * 8 * IC + (cc + c)) * 9;
#pragma unroll
            for (int oo = 0; oo < 8; ++oo) {
                const float* wr = wr0 + oo * IC * 9;
#pragma unroll
                for (int dy = 0; dy < 3; ++dy)
#pragma unroll
                    for (int dx = 0; dx < 3; ++dx) {
                        float wvv = wr[dy * 3 + dx];
#pragma unroll
                        for (int p = 0; p < 4; ++p)
                            acc[oo][p] = fmaf(wvv, xv[dy][p + dx], acc[oo][p]);
                    }
            }
        }
    }
    const int px = tx0 + pcq * 4, py = ty0 + pr;
#pragma unroll
    for (int oo = 0; oo < 8; ++oo) {
        int oc = wv * 8 + oo;
        float bb = bias[oc];
        float v0 = acc[oo][0] + bb, v1 = acc[oo][1] + bb;
        float v2 = acc[oo][2] + bb, v3 = acc[oo][3] + bb;
        if (RELU) {
            v0 = fmaxf(v0, 0.f); v1 = fmaxf(v1, 0.f);
            v2 = fmaxf(v2, 0.f); v3 = fmaxf(v3, 0.f);
        }
        ushort4 pk;
        pk.x = fbf(v0); pk.y = fbf(v1); pk.z = fbf(v2); pk.w = fbf(v3);
        *(ushort4*)(out + oc * HW + py * 128 + px) = pk;
    }
}

__global__ __launch_bounds__(256) void conv1_kernel(const void* __restrict__ vf,
                                                    const float* __restrict__ wf,
                                                    const int* __restrict__ flag,
                                                    unsigned short* __restrict__ hidden)
{
    int z = blockIdx.z, b = z >> 1, br = z & 1;
    const bool f32 = (*flag != 0);
    conv3x3_body<64, true>(vf, (long long)(b * 128 + br * 64) * HW, f32,
                           wf + (br ? WF_AW1 : WF_MW1), wf + (br ? WF_AB1 : WF_MB1),
                           hidden + (b * 64 + br * 32) * HW);
}

__global__ __launch_bounds__(256) void conv2_kernel(const unsigned short* __restrict__ hidden,
                                                    const float* __restrict__ wf,
                                                    unsigned short* __restrict__ comb)
{
    int z = blockIdx.z, b = z >> 2, br = (z >> 1) & 1, hf = z & 1;
    conv3x3_body<32, false>(hidden, (long long)(b * 64 + br * 32) * HW, false,
                            wf + (br ? WF_AW2 : WF_MW2) + hf * 32 * 32 * 9,
                            wf + (br ? WF_AB2 : WF_MB2) + hf * 32,
                            comb + (b * 128 + br * 64 + hf * 32) * HW);
}

// ---------------------------------------------------------------- K3: MHA (MFMA)
// LDS (ushort idx), 34,816 sh = 69,632 B:
//   Xs dbuf @0 / @2560   [64][40] e-chunk staging
//   head h @ HB = 5120 + h*7424: Q @HB [64][40] (P [64][72] overlays Q+K),
//     K @HB+2560 [64][40], V^T @HB+5120 [32][72]
//   O/D transpose area @5120 [64][136] (overlays heads 0-1 after barriers)
__global__ __launch_bounds__(256, 1) void mha_kernel(
    const unsigned short* __restrict__ comb,
    const float* __restrict__ wf,
    unsigned short* __restrict__ att)   // [n][tok][e] bf16, raw out-proj (no coef/bias)
{
    __shared__ unsigned short lds[34816];

    const unsigned short* wqkv = (const unsigned short*)(wf + WF_IPW); // [384][128] bf16
    const unsigned short* wo   = (const unsigned short*)(wf + WF_OPW); // [128][128] bf16

    const int n = blockIdx.x;
    const int ihw = n >> 2, bb = n & 3;
    const int ih = ihw / 31, iw = ihw - ih * 31;
    const int base = (bb * 128) * HW + (ih * 4) * 128 + iw * 4;
    const int t = threadIdx.x;
    const int lane = t & 63, quad = lane >> 4, l16 = lane & 15;
    const int hh = __builtin_amdgcn_readfirstlane(t >> 6);
    const int hb = hh * 32;
    const int HB = 5120 + hh * 7424;
    const int e_l = t >> 3, r8 = t & 7;

    // ---- QKV accumulators seeded with bias ----
    int rowb[6];
    f32x4 acc[6][4];
#pragma unroll
    for (int nt = 0; nt < 6; ++nt) {
        int rb = (nt < 2) ? (hb + nt * 16)
               : (nt < 4) ? (128 + hb + (nt - 2) * 16)
                          : (256 + hb + (nt - 4) * 16);
        rowb[nt] = rb;
        f32x4 b4;
        b4[0] = wf[WF_IPB + rb + quad * 4 + 0];
        b4[1] = wf[WF_IPB + rb + quad * 4 + 1];
        b4[2] = wf[WF_IPB + rb + quad * 4 + 2];
        b4[3] = wf[WF_IPB + rb + quad * 4 + 3];
#pragma unroll
        for (int mt = 0; mt < 4; ++mt) acc[nt][mt] = b4;
    }

    // ---- stage chunk 0 ----
    {
        const unsigned short* gp = comb + base + e_l * HW + r8 * 128;
        ushort4 a0 = *(const ushort4*)(gp);
        ushort4 a1 = *(const ushort4*)(gp + 4);
        unsigned short* xp = lds + (r8 * 8) * 40 + e_l;
        xp[0 * 40] = a0.x; xp[1 * 40] = a0.y; xp[2 * 40] = a0.z; xp[3 * 40] = a0.w;
        xp[4 * 40] = a1.x; xp[5 * 40] = a1.y; xp[6 * 40] = a1.z; xp[7 * 40] = a1.w;
    }
    __syncthreads();

    // ---- QKV: D = Wqkv . X^T, double-buffered staging ----
    for (int kc = 0; kc < 4; ++kc) {
        if (kc < 3) {   // prefetch next chunk into the other buffer
            const unsigned short* gp = comb + base + ((kc + 1) * 32 + e_l) * HW + r8 * 128;
            ushort4 a0 = *(const ushort4*)(gp);
            ushort4 a1 = *(const ushort4*)(gp + 4);
            unsigned short* xp = lds + ((kc + 1) & 1) * 2560 + (r8 * 8) * 40 + e_l;
            xp[0 * 40] = a0.x; xp[1 * 40] = a0.y; xp[2 * 40] = a0.z; xp[3 * 40] = a0.w;
            xp[4 * 40] = a1.x; xp[5 * 40] = a1.y; xp[6 * 40] = a1.z; xp[7 * 40] = a1.w;
        }
        const int xb = (kc & 1) * 2560;
        bf16x8 bx[4];
#pragma unroll
        for (int mt = 0; mt < 4; ++mt)
            bx[mt] = frag_ld(&lds[xb + (mt * 16 + l16) * 40 + quad * 8]);
#pragma unroll
        for (int nt = 0; nt < 6; ++nt) {
            bf16x8 aw = frag_ld(&wqkv[(rowb[nt] + l16) * 128 + kc * 32 + quad * 8]);
#pragma unroll
            for (int mt = 0; mt < 4; ++mt)
                acc[nt][mt] = MFMA16(aw, bx[mt], acc[nt][mt]);
        }
        __syncthreads();
    }

    // ---- write Q,K ([tok][d] s40) and V^T ([d][tok] s72) ----
#pragma unroll
    for (int nt = 0; nt < 2; ++nt)
#pragma unroll
        for (int mt = 0; mt < 4; ++mt) {
            int tok = mt * 16 + l16;
            *(uint2v*)&lds[HB + tok * 40 + nt * 16 + quad * 4] =
                pack4(acc[nt][mt][0], acc[nt][mt][1], acc[nt][mt][2], acc[nt][mt][3]);
            *(uint2v*)&lds[HB + 2560 + tok * 40 + nt * 16 + quad * 4] =
                pack4(acc[nt + 2][mt][0], acc[nt + 2][mt][1], acc[nt + 2][mt][2], acc[nt + 2][mt][3]);
        }
#pragma unroll
    for (int nt = 0; nt < 2; ++nt)
#pragma unroll
        for (int mt = 0; mt < 4; ++mt)
#pragma unroll
            for (int r = 0; r < 4; ++r)
                lds[HB + 5120 + (nt * 16 + quad * 4 + r) * 72 + mt * 16 + l16] =
                    fbf(acc[nt + 4][mt][r]);
    __asm__ volatile("s_waitcnt lgkmcnt(0)" ::: "memory");  // within-wave QKV handoff

    // ---- scores: S^T = K . Q^T ----
    bf16x8 ak[4], bq[4];
#pragma unroll
    for (int mtk = 0; mtk < 4; ++mtk)
        ak[mtk] = frag_ld(&lds[HB + 2560 + (mtk * 16 + l16) * 40 + quad * 8]);
#pragma unroll
    for (int ntq = 0; ntq < 4; ++ntq)
        bq[ntq] = frag_ld(&lds[HB + (ntq * 16 + l16) * 40 + quad * 8]);
    f32x4 sc[4][4];
    {
        f32x4 zz = {0.f, 0.f, 0.f, 0.f};
#pragma unroll
        for (int mtk = 0; mtk < 4; ++mtk)
#pragma unroll
            for (int ntq = 0; ntq < 4; ++ntq)
                sc[mtk][ntq] = MFMA16(ak[mtk], bq[ntq], zz);
    }

    // ---- softmax per q_tok; P [q_tok][k_tok] s72 overlays Q/K ----
    const float scale = 0.17677669529663687f;  // 32^-0.5
#pragma unroll
    for (int ntq = 0; ntq < 4; ++ntq) {
        float m0 = -1e30f;
#pragma unroll
        for (int mtk = 0; mtk < 4; ++mtk)
#pragma unroll
            for (int r = 0; r < 4; ++r) {
                sc[mtk][ntq][r] *= scale;
                m0 = fmaxf(m0, sc[mtk][ntq][r]);
            }
        m0 = fmaxf(m0, __shfl_xor(m0, 16));
        m0 = fmaxf(m0, __shfl_xor(m0, 32));
        float s0 = 0.f;
#pragma unroll
        for (int mtk = 0; mtk < 4; ++mtk)
#pragma unroll
            for (int r = 0; r < 4; ++r) {
                float p = __expf(sc[mtk][ntq][r] - m0);
                sc[mtk][ntq][r] = p;
                s0 += p;
            }
        s0 += __shfl_xor(s0, 16);
        s0 += __shfl_xor(s0, 32);
        float inv = 1.f / s0;
#pragma unroll
        for (int mtk = 0; mtk < 4; ++mtk)
            *(uint2v*)&lds[HB + (ntq * 16 + l16) * 72 + mtk * 16 + quad * 4] =
                pack4(sc[mtk][ntq][0] * inv, sc[mtk][ntq][1] * inv,
                      sc[mtk][ntq][2] * inv, sc[mtk][ntq][3] * inv);
    }
    __asm__ volatile("s_waitcnt lgkmcnt(0)" ::: "memory");  // P handoff

    // ---- O = P . V ----
    f32x4 ov[4][2];
#pragma unroll
    for (int mt = 0; mt < 4; ++mt)
#pragma unroll
        for (int nv = 0; nv < 2; ++nv) { f32x4 zz = {0.f,0.f,0.f,0.f}; ov[mt][nv] = zz; }
#pragma unroll
    for (int ks = 0; ks < 2; ++ks) {
        bf16x8 ap[4];
#pragma unroll
        for (int mt = 0; mt < 4; ++mt)
            ap[mt] = frag_ld(&lds[HB + (mt * 16 + l16) * 72 + ks * 32 + quad * 8]);
#pragma unroll
        for (int nv = 0; nv < 2; ++nv) {
            bf16x8 bv = frag_ld(&lds[HB + 5120 + (nv * 16 + l16) * 72 + ks * 32 + quad * 8]);
#pragma unroll
            for (int mt = 0; mt < 4; ++mt)
                ov[mt][nv] = MFMA16(ap[mt], bv, ov[mt][nv]);
        }
    }
    __syncthreads();  // all waves done with QKV/P/V before O overlays heads 0-1

    // ---- O -> LDS [tok][e] s136 @5120 ----
#pragma unroll
    for (int mt = 0; mt < 4; ++mt)
#pragma unroll
        for (int nv = 0; nv < 2; ++nv)
#pragma unroll
            for (int r = 0; r < 4; ++r)
                lds[5120 + (mt * 16 + quad * 4 + r) * 136 + hb + nv * 16 + l16] =
                    fbf(ov[mt][nv][r]);
    __syncthreads();

    // ---- out-proj: D = O . Wo^T (raw; coef+bias applied in fuse) ----
    f32x4 dp[4][2];
#pragma unroll
    for (int mt = 0; mt < 4; ++mt)
#pragma unroll
        for (int nl = 0; nl < 2; ++nl) { f32x4 zz = {0.f,0.f,0.f,0.f}; dp[mt][nl] = zz; }
#pragma unroll
    for (int ks = 0; ks < 4; ++ks) {
        bf16x8 af[4];
#pragma unroll
        for (int mt = 0; mt < 4; ++mt)
            af[mt] = frag_ld(&lds[5120 + (mt * 16 + l16) * 136 + ks * 32 + quad * 8]);
#pragma unroll
        for (int nl = 0; nl < 2; ++nl) {
            int erow = hb + nl * 16 + l16;
            bf16x8 bw = frag_ld(&wo[erow * 128 + ks * 32 + quad * 8]);
#pragma unroll
            for (int mt = 0; mt < 4; ++mt)
                dp[mt][nl] = MFMA16(af[mt], bw, dp[mt][nl]);
        }
    }
    __syncthreads();  // all O reads done before D overlays the same area

    // ---- D -> LDS [tok][e] s136 @5120 ----
#pragma unroll
    for (int mt = 0; mt < 4; ++mt)
#pragma unroll
        for (int nl = 0; nl < 2; ++nl)
#pragma unroll
            for (int r = 0; r < 4; ++r)
                lds[5120 + (mt * 16 + quad * 4 + r) * 136 + hb + nl * 16 + l16] =
                    fbf(dp[mt][nl][r]);
    __syncthreads();

    // ---- coalesced att store: thread covers (tok = t>>2, 32 e's) ----
    {
        const int tok2 = t >> 2, eo = (t & 3) * 32;
        unsigned short* op = att + (size_t)n * 8192 + tok2 * 128 + eo;
        const unsigned short* lp = lds + 5120 + tok2 * 136 + eo;
#pragma unroll
        for (int k4 = 0; k4 < 4; ++k4)
            *(uint4v*)(op + k4 * 8) = *(const uint4v*)(lp + k4 * 8);
    }
}

// ---------------------------------------------------------------- K4: fuse
// gathers <=4 covering windows per pixel with closed-form scan coefs.
__global__ __launch_bounds__(256) void fuse_kernel(
    const unsigned short* __restrict__ comb,
    const unsigned short* __restrict__ att,   // [n][tok][e] raw out-proj
    const void* __restrict__ vf,
    const float* __restrict__ wf,
    const int* __restrict__ flag,
    void* __restrict__ outp)
{
    __shared__ float enhs[128][65];
    __shared__ float fws[64][65];
    const float* fcw = wf + WF_FCW;
    const float* fcb = wf + WF_FCB;
    const bool f32 = (*flag != 0);
    const int t = threadIdx.x;
    const int wl = t & 63;
    const int eg = __builtin_amdgcn_readfirstlane(t >> 6);
    const int h = blockIdx.y, b = blockIdx.z;
    const int w = blockIdx.x * 64 + wl;

    const int mh = h >> 2, mw = w >> 2;
    const bool vh0 = (mh >= 1), vh1 = (mh <= 30);
    const bool vw0 = (mw >= 1), vw1 = (mw <= 30);
    const int k = ((int)vh0 + (int)vh1) * ((int)vw0 + (int)vw1); // 1,2,4
    const float base7 = (k == 1) ? 0.7f : (k == 2) ? 0.49f : 0.2401f;
    const float bias_c = 1.f - base7;  // sum_j coef_j (out-proj bias weight)

    float cw[4]; int coff[4];
    {
        const bool vs[4] = { vh0 && vw0, vh0 && vw1, vh1 && vw0, vh1 && vw1 };
        const int ihc[4] = { mh - 1, mh - 1, mh, mh };
        const int iwc[4] = { mw - 1, mw, mw - 1, mw };
        int j = 0;
#pragma unroll
        for (int s = 0; s < 4; ++s) {
            if (vs[s]) {
                ++j;
                int e2 = k - j;  // 0..3
                float pw = (e2 == 0) ? 1.f : (e2 == 1) ? 0.7f : (e2 == 2) ? 0.49f : 0.343f;
                cw[s] = 0.3f * pw;
                int nn = (ihc[s] * 31 + iwc[s]) * 4 + b;
                int ll = (h - 4 * ihc[s]) * 8 + (w - 4 * iwc[s]);
                coff[s] = nn * 8192 + ll * 128;
            } else { cw[s] = 0.f; coff[s] = 0; }
        }
    }

    const int cbase = (b * 128) * HW + h * 128 + w;
    const int e0 = eg * 32;
#pragma unroll
    for (int i8 = 0; i8 < 4; ++i8) {
        float av[8];
#pragma unroll
        for (int j = 0; j < 8; ++j)
            av[j] = bias_c * wf[WF_OPB + e0 + i8 * 8 + j];
#pragma unroll
        for (int s = 0; s < 4; ++s) {
            uint4v u = *(const uint4v*)(att + coff[s] + e0 + i8 * 8);
            float x[8];
            unp8(u, x);
#pragma unroll
            for (int j = 0; j < 8; ++j)
                av[j] = fmaf(cw[s], x[j], av[j]);
        }
#pragma unroll
        for (int j = 0; j < 8; ++j) {
            const int e = e0 + i8 * 8 + j;
            enhs[e][wl] = fmaf(base7, bfu(comb[cbase + e * HW]), av[j]);
        }
    }
    __syncthreads();

    float a2[16];
    const int co0 = eg * 16;
#pragma unroll
    for (int i = 0; i < 16; ++i) a2[i] = fcb[co0 + i];
    for (int e = 0; e < 128; ++e) {
        float x = enhs[e][wl];
#pragma unroll
        for (int i = 0; i < 16; ++i)
            a2[i] = fmaf(x, fcw[(co0 + i) * 128 + e], a2[i]);
    }
#pragma unroll
    for (int i = 0; i < 16; ++i)
        fws[co0 + i][wl] = 1.f / (1.f + __expf(-a2[i]));
    __syncthreads();

#pragma unroll
    for (int i = 0; i < 32; ++i) {
        const int e = eg * 32 + i;
        const int idx = cbase + e * HW;
        float val = enhs[e][wl] * fws[e & 63][wl] + ldin(vf, idx, f32);
        if (f32) ((float*)outp)[idx] = val;
        else     ((unsigned short*)outp)[idx] = fbf(val);
    }
}

// ---------------------------------------------------------------------------
extern "C" void kernel_launch(void* const* d_in, const int* in_sizes, int n_in,
                              void* d_out, int out_size, void* d_ws, size_t ws_size,
                              hipStream_t stream)
{
    const void* vf  = d_in[0];
    const void* mw1 = d_in[1];
    const void* mb1 = d_in[2];
    const void* mw2 = d_in[3];
    const void* mb2 = d_in[4];
    const void* aw1 = d_in[5];
    const void* ab1 = d_in[6];
    const void* aw2 = d_in[7];
    const void* ab2 = d_in[8];
    const void* ipw = d_in[9];
    const void* ipb = d_in[10];
    const void* opw = d_in[11];
    const void* opb = d_in[12];
    const void* fcw = d_in[13];
    const void* fcb = d_in[14];

    // ws layout (80,351,232 B total)
    int* flag = (int*)d_ws;                                         // @0
    float* wf = (float*)((char*)d_ws + 1024);                       // 592,896 B
    unsigned short* comb = (unsigned short*)((char*)d_ws + 593920); // 16,777,216 B
    unsigned short* hidden = (unsigned short*)((char*)d_ws + 17371136); // 8.39 MB
    unsigned short* att = (unsigned short*)((char*)d_ws + 17371136);    // 62,980,096 B (overlays hidden)

    detect_kernel<<<1, 256, 0, stream>>>((const unsigned short*)vf, flag);
    cvtw_kernel<<<(WF_TOTAL + 255) / 256, 256, 0, stream>>>(
        ipw, ipb, opw, opb, fcw, fcb, mw1, mb1, aw1, ab1, mw2, mb2, aw2, ab2, flag, wf);
    conv1_kernel<<<dim3(4, 16, 8), 256, 0, stream>>>(vf, wf, flag, hidden);
    conv2_kernel<<<dim3(4, 16, 16), 256, 0, stream>>>(hidden, wf, comb);
    mha_kernel<<<NSEQ, 256, 0, stream>>>(comb, wf, att);
    fuse_kernel<<<dim3(2, 128, 4), 256, 0, stream>>>(comb, att, vf, wf, flag, d_out);
}